// Round 3
// baseline (1301.291 us; speedup 1.0000x reference)
//
#include <hip/hip_runtime.h>
#include <hip/hip_bf16.h>

typedef unsigned short ushort_t;
typedef unsigned int uint_t;
typedef short short8 __attribute__((ext_vector_type(8)));
typedef float floatx4 __attribute__((ext_vector_type(4)));

// ---------- bf16 helpers (raw ushort storage) ----------
__device__ inline float b2f(ushort_t u){
    uint_t v = ((uint_t)u) << 16;
    return __uint_as_float(v);
}
__device__ inline ushort_t f2b(float f){
    uint_t v = __float_as_uint(f);
    uint_t r = (v + 0x7FFFu + ((v >> 16) & 1u)) >> 16;  // RNE
    return (ushort_t)r;
}
__device__ inline void unpack8(uint4 u, float* f){
    uint_t w[4] = {u.x, u.y, u.z, u.w};
    #pragma unroll
    for (int i = 0; i < 4; ++i){
        f[2*i]   = __uint_as_float(w[i] << 16);
        f[2*i+1] = __uint_as_float(w[i] & 0xFFFF0000u);
    }
}
__device__ inline uint4 pack8(const float* f){
    uint4 o;
    uint_t w[4];
    #pragma unroll
    for (int i = 0; i < 4; ++i)
        w[i] = (uint_t)f2b(f[2*i]) | ((uint_t)f2b(f[2*i+1]) << 16);
    o.x = w[0]; o.y = w[1]; o.z = w[2]; o.w = w[3];
    return o;
}
__device__ inline ushort4 cvt4(float4 v){
    ushort4 o;
    o.x = f2b(v.x); o.y = f2b(v.y); o.z = f2b(v.z); o.w = f2b(v.w);
    return o;
}

// ---------- constants ----------
// B=32, P=14, WS=7, SS=3, NW=4 windows/img, N_WIN=49, H=12, hd=64
// C=768, HID=3072, rows M = 32*196 = 6272
#define MROWS 6272
#define CDIM  768
#define HID   3072
#define QKV3  2304

// ---------- fp32 -> bf16 cast (weights) ----------
__global__ __launch_bounds__(256) void cvt_f2b(const float4* __restrict__ in,
                                               ushort4* __restrict__ out, int n4){
    int i = blockIdx.x * 256 + threadIdx.x;
    if (i < n4) out[i] = cvt4(in[i]);
}

// ---------- window gather: x fp32 (B,197,C) -> win bf16 (128*49, C), shifted ----------
__global__ __launch_bounds__(256) void gather_win(const float4* __restrict__ x,
                                                  ushort4* __restrict__ win){
    int idx = blockIdx.x * 256 + threadIdx.x;           // over 6272*192 groups of 4
    if (idx >= MROWS * 192) return;
    int r  = idx / 192, c4 = idx % 192;
    int w  = r / 49,  t  = r % 49;
    int b  = w >> 2,  wi = w & 3;
    int wy = wi >> 1, wx = wi & 1;
    int ty = t / 7,   tx = t % 7;
    int ys = (wy*7 + ty + 3) % 14;                       // roll(-3)
    int xs = (wx*7 + tx + 3) % 14;
    win[idx] = cvt4(x[(size_t)b*197*192 + (size_t)(1 + ys*14 + xs)*192 + c4]);
}

// ---------- reverse: proj fp32 (window layout) -> f fp32 + fbf bf16 (spatial) ----------
__global__ __launch_bounds__(256) void scatter_f(const float4* __restrict__ proj,
                                                 float4* __restrict__ f,
                                                 ushort4* __restrict__ fbf){
    int idx = blockIdx.x * 256 + threadIdx.x;
    if (idx >= MROWS * 192) return;
    int r  = idx / 192, c4 = idx % 192;
    int w  = r / 49,  t  = r % 49;
    int b  = w >> 2,  wi = w & 3;
    int wy = wi >> 1, wx = wi & 1;
    int ty = t / 7,   tx = t % 7;
    int yd = (wy*7 + ty + 3) % 14;                       // roll(+3) inverse
    int xd = (wx*7 + tx + 3) % 14;
    float4 v = proj[idx];
    size_t off = (size_t)b*196*192 + (size_t)(yd*14 + xd)*192 + c4;
    f[off] = v;
    fbf[off] = cvt4(v);
}

// ---------- MFMA GEMM: C(MxN) = A(MxK) @ B(NxK)^T (+bias), bf16 in, fp32 acc ----------
// m93/m97 structure: 128x128 tile, BK=32, 4 waves (2x2 of 64x64), global_load_lds w=16
// output: Cb (bf16) if non-null, else Cf (fp32)
__global__ __launch_bounds__(256) void gemm_bt(const ushort_t* __restrict__ A,
                                               const ushort_t* __restrict__ B,
                                               ushort_t* __restrict__ Cb,
                                               float* __restrict__ Cf,
                                               int M, int N, int K,
                                               const float* __restrict__ bias){
    __shared__ __align__(16) ushort_t As[128*32];
    __shared__ __align__(16) ushort_t Bs[128*32];
    const int tid  = threadIdx.x;
    const int lane = tid & 63;
    const int wid  = tid >> 6;
    const int m0 = blockIdx.y * 128;
    const int n0 = blockIdx.x * 128;
    const int wm = (wid >> 1) * 64;
    const int wn = (wid & 1) * 64;

    floatx4 acc[4][4] = {};

    for (int k0 = 0; k0 < K; k0 += 32){
        __syncthreads();   // previous iter's ds_reads done before overwrite
        #pragma unroll
        for (int j = 0; j < 2; ++j){
            int ch  = wid*2 + j;                 // 0..7, wave-uniform
            int row = ch*16 + (lane >> 2);
            int col = (lane & 3) * 8;
            const ushort_t* gA = A + (size_t)(m0 + row)*K + k0 + col;
            const ushort_t* gB = B + (size_t)(n0 + row)*K + k0 + col;
            __builtin_amdgcn_global_load_lds(
                (const __attribute__((address_space(1))) void*)gA,
                (__attribute__((address_space(3))) void*)(As + ch*512 + lane*8), 16, 0, 0);
            __builtin_amdgcn_global_load_lds(
                (const __attribute__((address_space(1))) void*)gB,
                (__attribute__((address_space(3))) void*)(Bs + ch*512 + lane*8), 16, 0, 0);
        }
        __syncthreads();   // drains vmcnt: staged data visible

        short8 af[4], bfr[4];
        const int fr = lane & 15;
        const int co = (lane >> 4) * 8;
        #pragma unroll
        for (int i = 0; i < 4; ++i){
            af[i]  = *(const short8*)(As + (wm + i*16 + fr)*32 + co);
            bfr[i] = *(const short8*)(Bs + (wn + i*16 + fr)*32 + co);
        }
        #pragma unroll
        for (int i = 0; i < 4; ++i)
            #pragma unroll
            for (int j = 0; j < 4; ++j)
                acc[i][j] = __builtin_amdgcn_mfma_f32_16x16x32_bf16(af[i], bfr[j], acc[i][j], 0, 0, 0);
    }

    // epilogue: C/D layout col=lane&15, row=(lane>>4)*4+r  [m89-verified]
    #pragma unroll
    for (int i = 0; i < 4; ++i){
        int grow = m0 + wm + i*16 + (lane >> 4)*4;
        #pragma unroll
        for (int j = 0; j < 4; ++j){
            int gcol = n0 + wn + j*16 + (lane & 15);
            float bv = bias ? bias[gcol] : 0.f;
            if (Cb){
                #pragma unroll
                for (int r = 0; r < 4; ++r)
                    Cb[(size_t)(grow + r)*N + gcol] = f2b(acc[i][j][r] + bv);
            } else {
                #pragma unroll
                for (int r = 0; r < 4; ++r)
                    Cf[(size_t)(grow + r)*N + gcol] = acc[i][j][r] + bv;
            }
        }
    }
}

// ---------- attention: per (head, window) block; softmax(QK^T*s + bias + mask) @ V ----------
__global__ __launch_bounds__(256) void attn_kernel(const ushort_t* __restrict__ qkv,
                                                   ushort_t* __restrict__ outp,
                                                   const float* __restrict__ rpb){
    __shared__ float qs[49*65];   // +1 padding banks (stride 65 % 32 != 0)
    __shared__ float ks[49*65];
    __shared__ float vs[49*65];
    __shared__ float Ss[49*50];
    __shared__ int   code[49];
    const int tid = threadIdx.x;
    const int h = blockIdx.x;     // 0..11
    const int w = blockIdx.y;     // 0..127
    const int wi = w & 3;
    const int wy = wi >> 1, wx = wi & 1;

    if (tid < 49){
        int ty = tid / 7, tx = tid % 7;
        int gy = wy*7 + ty, gx = wx*7 + tx;
        int ch = (gy < 7) ? 0 : (gy < 11 ? 1 : 2);
        int cw = (gx < 7) ? 0 : (gx < 11 ? 1 : 2);
        code[tid] = ch*3 + cw;
    }
    for (int idx = tid; idx < 49*64; idx += 256){
        int t = idx >> 6, d = idx & 63;
        size_t base = (size_t)(w*49 + t)*QKV3 + h*64 + d;
        qs[t*65 + d] = b2f(qkv[base]) * 0.125f;          // scale = hd^-0.5
        ks[t*65 + d] = b2f(qkv[base + 768]);
        vs[t*65 + d] = b2f(qkv[base + 1536]);
    }
    __syncthreads();

    for (int idx = tid; idx < 49*49; idx += 256){
        int qi = idx / 49, ki = idx - qi*49;
        const float* qr = qs + qi*65;
        const float* kr = ks + ki*65;
        float a = 0.f;
        #pragma unroll 8
        for (int d = 0; d < 64; ++d) a += qr[d]*kr[d];
        int qy = qi/7, qx = qi%7, ky = ki/7, kx = ki%7;
        int ridx = (qy - ky + 6)*13 + (qx - kx + 6);
        a += rpb[ridx*12 + h];
        if (code[qi] != code[ki]) a -= 100.f;
        Ss[qi*50 + ki] = a;
    }
    __syncthreads();

    if (tid < 49){
        float* row = Ss + tid*50;
        float m = row[0];
        for (int k = 1; k < 49; ++k) m = fmaxf(m, row[k]);
        float s = 0.f;
        for (int k = 0; k < 49; ++k){ float e = __expf(row[k] - m); row[k] = e; s += e; }
        float inv = 1.f / s;
        for (int k = 0; k < 49; ++k) row[k] *= inv;
    }
    __syncthreads();

    for (int idx = tid; idx < 49*64; idx += 256){
        int qi = idx >> 6, d = idx & 63;
        const float* sr = Ss + qi*50;
        const float* vc = vs + d;
        float a = 0.f;
        #pragma unroll 7
        for (int k = 0; k < 49; ++k) a += sr[k]*vc[k*65];
        outp[(size_t)(w*49 + qi)*CDIM + h*64 + d] = f2b(a);
    }
}

// ---------- BN over batch+spatial: stats (atomic partial sums) ----------
__global__ void zero_f32(float* __restrict__ p, int n){
    int i = blockIdx.x*256 + threadIdx.x;
    if (i < n) p[i] = 0.f;
}
__global__ __launch_bounds__(256) void bn_stats(const ushort_t* __restrict__ X,
                                                float* __restrict__ sums, int Cch){
    int c  = blockIdx.x*256 + threadIdx.x;
    int r0 = blockIdx.y * 784;                 // 6272/8 row-splits
    float s = 0.f, s2 = 0.f;
    for (int r = r0; r < r0 + 784; ++r){
        float v = b2f(X[(size_t)r*Cch + c]);
        s += v; s2 += v*v;
    }
    atomicAdd(&sums[c], s);
    atomicAdd(&sums[Cch + c], s2);
}
__global__ __launch_bounds__(256) void bn_stats_f(const float* __restrict__ X,
                                                  float* __restrict__ sums, int Cch){
    int c  = blockIdx.x*256 + threadIdx.x;
    int r0 = blockIdx.y * 784;
    float s = 0.f, s2 = 0.f;
    for (int r = r0; r < r0 + 784; ++r){
        float v = X[(size_t)r*Cch + c];
        s += v; s2 += v*v;
    }
    atomicAdd(&sums[c], s);
    atomicAdd(&sums[Cch + c], s2);
}
__global__ void bn_finalize(float* __restrict__ sums, const float* __restrict__ g,
                            const float* __restrict__ b, int Cch){
    int c = blockIdx.x*256 + threadIdx.x;
    if (c >= Cch) return;
    float mean = sums[c] * (1.f/6272.f);
    float var  = sums[Cch + c] * (1.f/6272.f) - mean*mean;
    float sc = g[c] * rsqrtf(var + 1e-5f);
    sums[c] = sc;
    sums[Cch + c] = b[c] - mean*sc;            // y = x*sc + shift
}
// in-place scale/shift (+hswish), 8 bf16 per thread
__global__ __launch_bounds__(256) void bn_apply(ushort_t* __restrict__ X,
                                                const float* __restrict__ ss,
                                                int Cch, int total8, int act){
    int idx = blockIdx.x*256 + threadIdx.x;
    if (idx >= total8) return;
    int c8 = idx % (Cch/8);
    uint4 u = ((uint4*)X)[idx];
    float f[8]; unpack8(u, f);
    int cb = c8*8;
    #pragma unroll
    for (int e = 0; e < 8; ++e){
        float y = f[e]*ss[cb+e] + ss[Cch+cb+e];
        if (act) y = y * fminf(fmaxf(y + 3.f, 0.f), 6.f) * (1.f/6.f);
        f[e] = y;
    }
    ((uint4*)X)[idx] = pack8(f);
}

// ---------- depthwise 3x3 SAME conv, layout (b, y, x, c) channel-contiguous ----------
__global__ __launch_bounds__(256) void dwconv(const ushort_t* __restrict__ in,
                                              const float* __restrict__ wgt,
                                              ushort_t* __restrict__ out){
    int blk = blockIdx.x;                      // 0..6271 = b*196+p
    int b = blk / 196, p = blk % 196;
    int y = p / 14, x = p % 14;
    const size_t base = (size_t)b * 196 * HID;
    for (int c = threadIdx.x; c < HID; c += 256){
        float a = 0.f;
        #pragma unroll
        for (int i = 0; i < 3; ++i){
            int yy = y + i - 1;
            if (yy < 0 || yy >= 14) continue;
            #pragma unroll
            for (int j = 0; j < 3; ++j){
                int xx = x + j - 1;
                if (xx < 0 || xx >= 14) continue;
                a += b2f(in[base + (size_t)(yy*14 + xx)*HID + c]) * wgt[c*9 + i*3 + j];
            }
        }
        out[base + (size_t)p*HID + c] = f2b(a);
    }
}

// ---------- SE ----------
__global__ __launch_bounds__(256) void se_mean(const ushort_t* __restrict__ X,
                                               float* __restrict__ s){
    int b = blockIdx.x;                        // 0..31
    int c = blockIdx.y*256 + threadIdx.x;      // 0..3071
    float a = 0.f;
    for (int p = 0; p < 196; ++p)
        a += b2f(X[((size_t)b*196 + p)*HID + c]);
    s[b*HID + c] = a * (1.f/196.f);
}
__global__ __launch_bounds__(256) void se_fc(const float* __restrict__ in,
                                             const float* __restrict__ w,
                                             const float* __restrict__ bias,
                                             float* __restrict__ out,
                                             int IN, int OUT, int mode){
    int b = blockIdx.x;
    int n = blockIdx.y*256 + threadIdx.x;
    if (n >= OUT) return;
    const float* wr = w + (size_t)n * IN;
    const float* xr = in + (size_t)b * IN;
    float a = bias[n];
    for (int k = 0; k < IN; k += 2)
        a += xr[k]*wr[k] + xr[k+1]*wr[k+1];
    if (mode == 0) a = fmaxf(a, 0.f);                          // relu
    else           a = fminf(fmaxf(a + 3.f, 0.f), 6.f) * (1.f/6.f);  // hsig
    out[b*OUT + n] = a;
}
__global__ __launch_bounds__(256) void se_scale(ushort_t* __restrict__ X,
                                                const float* __restrict__ s2){
    int idx = blockIdx.x*256 + threadIdx.x;    // over 6272*384 uint4
    if (idx >= MROWS * (HID/8)) return;
    int r = idx / (HID/8), c8 = idx % (HID/8);
    int b = r / 196;
    uint4 u = ((uint4*)X)[idx];
    float f[8]; unpack8(u, f);
    const float* sp = s2 + b*HID + c8*8;
    #pragma unroll
    for (int e = 0; e < 8; ++e) f[e] *= sp[e];
    ((uint4*)X)[idx] = pack8(f);
}

// ---------- final: out = concat(cls, f + bn3(h4)), ALL fp32 ----------
__global__ __launch_bounds__(256) void final_k(const float4* __restrict__ xin,
                                               const float4* __restrict__ f,
                                               const float4* __restrict__ h4,
                                               const float* __restrict__ ss,
                                               float4* __restrict__ outp){
    int idx = blockIdx.x*256 + threadIdx.x;    // over 32*197*192 float4
    if (idx >= 32*197*192) return;
    int b = idx / (197*192);
    int rem = idx % (197*192);
    int n = rem / 192, c4 = rem % 192;
    if (n == 0){ outp[idx] = xin[idx]; return; }
    size_t off = ((size_t)b*196 + n - 1)*192 + c4;
    float4 hv = h4[off];
    float4 fv = f[off];
    float4 o;
    int c = c4*4;
    o.x = fv.x + hv.x*ss[c+0] + ss[CDIM + c+0];
    o.y = fv.y + hv.y*ss[c+1] + ss[CDIM + c+1];
    o.z = fv.z + hv.z*ss[c+2] + ss[CDIM + c+2];
    o.w = fv.w + hv.w*ss[c+3] + ss[CDIM + c+3];
    outp[idx] = o;
}

extern "C" void kernel_launch(void* const* d_in, const int* in_sizes, int n_in,
                              void* d_out, int out_size, void* d_ws, size_t ws_size,
                              hipStream_t stream){
    const float* x      = (const float*)d_in[0];
    const float* w_qkv  = (const float*)d_in[1];
    const float* w_proj = (const float*)d_in[2];
    const float* b_proj = (const float*)d_in[3];
    const float* rpb    = (const float*)d_in[4];
    const float* pw1_w  = (const float*)d_in[5];
    const float* bn1_g  = (const float*)d_in[6];
    const float* bn1_b  = (const float*)d_in[7];
    const float* dw_w   = (const float*)d_in[8];
    const float* bn2_g  = (const float*)d_in[9];
    const float* bn2_b  = (const float*)d_in[10];
    const float* se_w1  = (const float*)d_in[11];
    const float* se_b1  = (const float*)d_in[12];
    const float* se_w2  = (const float*)d_in[13];
    const float* se_b2  = (const float*)d_in[14];
    const float* pw2_w  = (const float*)d_in[15];
    const float* bn3_g  = (const float*)d_in[16];
    const float* bn3_b  = (const float*)d_in[17];

    char* ws = (char*)d_ws;
    // lifetime-overlaid layout (bytes), total ~97.3 MB:
    //  region1 [0, 38535168):        win[0,9.6M)+qkv[9.6M,38.5M) -> ha -> {h4 fp32 [0,19.3M), pw2b [19.3M,24.0M)}
    //  region2 [38535168, 77070336): attnb[38.5M,48.2M) + proj f32 [48.2M,67.4M) + pw1b [67.4M,72.2M) -> fbf[38.5M,48.2M) -> hb (full)
    //  region3 [77070336, 96337920): wqkvb+wprojb (early) -> f fp32 (step6..final)
    //  [96337920, ~97.3M):           stats/s/s1/s2 fp32 scratch
    ushort_t* win    = (ushort_t*)(ws + 0);
    ushort_t* qkv    = (ushort_t*)(ws + 9633792);
    ushort_t* ha     = (ushort_t*)(ws + 0);
    float*    h4     = (float*)(ws + 0);
    ushort_t* pw2b   = (ushort_t*)(ws + 19267584);
    ushort_t* attnb  = (ushort_t*)(ws + 38535168);
    ushort_t* fbf    = (ushort_t*)(ws + 38535168);
    float*    proj   = (float*)(ws + 48168960);
    ushort_t* pw1b   = (ushort_t*)(ws + 67436544);
    ushort_t* hb     = (ushort_t*)(ws + 38535168);
    ushort_t* wqkvb  = (ushort_t*)(ws + 77070336);
    ushort_t* wprojb = (ushort_t*)(ws + 80609280);
    float*    f      = (float*)(ws + 77070336);
    float*    stats  = (float*)(ws + 96337920);
    float*    s      = (float*)(ws + 96362496);
    float*    s1     = (float*)(ws + 96755712);
    float*    s2     = (float*)(ws + 96854016);

    const int vec_rows = (MROWS*192 + 255)/256;
    const int vec_hid8 = (MROWS*(HID/8) + 255)/256;

    // weight casts (live in regions not yet written)
    cvt_f2b<<<(QKV3*CDIM/4 + 255)/256, 256, 0, stream>>>((const float4*)w_qkv, (ushort4*)wqkvb, QKV3*CDIM/4);
    cvt_f2b<<<(CDIM*CDIM/4 + 255)/256, 256, 0, stream>>>((const float4*)w_proj, (ushort4*)wprojb, CDIM*CDIM/4);
    cvt_f2b<<<(HID*CDIM/4 + 255)/256, 256, 0, stream>>>((const float4*)pw1_w, (ushort4*)pw1b, HID*CDIM/4);

    // attention half
    gather_win<<<vec_rows, 256, 0, stream>>>((const float4*)x, (ushort4*)win);
    gemm_bt<<<dim3(QKV3/128, MROWS/128), 256, 0, stream>>>(win, wqkvb, qkv, nullptr, MROWS, QKV3, CDIM, nullptr);
    attn_kernel<<<dim3(12, 128), 256, 0, stream>>>(qkv, attnb, rpb);
    gemm_bt<<<dim3(CDIM/128, MROWS/128), 256, 0, stream>>>(attnb, wprojb, nullptr, proj, MROWS, CDIM, CDIM, b_proj);
    scatter_f<<<vec_rows, 256, 0, stream>>>((const float4*)proj, (float4*)f, (ushort4*)fbf);

    // ConvFFN half
    gemm_bt<<<dim3(HID/128, MROWS/128), 256, 0, stream>>>(fbf, pw1b, ha, nullptr, MROWS, HID, CDIM, nullptr);
    zero_f32<<<24, 256, 0, stream>>>(stats, 2*HID);
    bn_stats<<<dim3(HID/256, 8), 256, 0, stream>>>(ha, stats, HID);
    bn_finalize<<<HID/256, 256, 0, stream>>>(stats, bn1_g, bn1_b, HID);
    bn_apply<<<vec_hid8, 256, 0, stream>>>(ha, stats, HID, MROWS*(HID/8), 1);

    dwconv<<<MROWS, 256, 0, stream>>>(ha, dw_w, hb);
    cvt_f2b<<<(CDIM*HID/4 + 255)/256, 256, 0, stream>>>((const float4*)pw2_w, (ushort4*)pw2b, CDIM*HID/4);  // ha dead now
    zero_f32<<<24, 256, 0, stream>>>(stats, 2*HID);
    bn_stats<<<dim3(HID/256, 8), 256, 0, stream>>>(hb, stats, HID);
    bn_finalize<<<HID/256, 256, 0, stream>>>(stats, bn2_g, bn2_b, HID);
    bn_apply<<<vec_hid8, 256, 0, stream>>>(hb, stats, HID, MROWS*(HID/8), 1);

    se_mean<<<dim3(32, HID/256), 256, 0, stream>>>(hb, s);
    se_fc<<<dim3(32, 3), 256, 0, stream>>>(s, se_w1, se_b1, s1, HID, 768, 0);
    se_fc<<<dim3(32, 12), 256, 0, stream>>>(s1, se_w2, se_b2, s2, 768, HID, 1);
    se_scale<<<vec_hid8, 256, 0, stream>>>(hb, s2);

    gemm_bt<<<dim3(CDIM/128, MROWS/128), 256, 0, stream>>>(hb, pw2b, nullptr, h4, MROWS, CDIM, HID, nullptr);
    zero_f32<<<6, 256, 0, stream>>>(stats, 2*CDIM);
    bn_stats_f<<<dim3(CDIM/256, 8), 256, 0, stream>>>(h4, stats, CDIM);
    bn_finalize<<<CDIM/256, 256, 0, stream>>>(stats, bn3_g, bn3_b, CDIM);
    final_k<<<(32*197*192 + 255)/256, 256, 0, stream>>>((const float4*)x, (const float4*)f, (const float4*)h4, stats, (float4*)d_out);
}

// Round 4
// 966.690 us; speedup vs baseline: 1.3461x; 1.3461x over previous
//
#include <hip/hip_runtime.h>
#include <hip/hip_bf16.h>

typedef unsigned short ushort_t;
typedef unsigned int uint_t;
typedef short short8 __attribute__((ext_vector_type(8)));
typedef float floatx4 __attribute__((ext_vector_type(4)));

// ---------- bf16 helpers (raw ushort storage) ----------
__device__ inline float b2f(ushort_t u){
    uint_t v = ((uint_t)u) << 16;
    return __uint_as_float(v);
}
__device__ inline ushort_t f2b(float f){
    uint_t v = __float_as_uint(f);
    uint_t r = (v + 0x7FFFu + ((v >> 16) & 1u)) >> 16;  // RNE
    return (ushort_t)r;
}
__device__ inline void unpack8(uint4 u, float* f){
    uint_t w[4] = {u.x, u.y, u.z, u.w};
    #pragma unroll
    for (int i = 0; i < 4; ++i){
        f[2*i]   = __uint_as_float(w[i] << 16);
        f[2*i+1] = __uint_as_float(w[i] & 0xFFFF0000u);
    }
}
__device__ inline uint4 pack8(const float* f){
    uint4 o;
    uint_t w[4];
    #pragma unroll
    for (int i = 0; i < 4; ++i)
        w[i] = (uint_t)f2b(f[2*i]) | ((uint_t)f2b(f[2*i+1]) << 16);
    o.x = w[0]; o.y = w[1]; o.z = w[2]; o.w = w[3];
    return o;
}
__device__ inline ushort4 cvt4(float4 v){
    ushort4 o;
    o.x = f2b(v.x); o.y = f2b(v.y); o.z = f2b(v.z); o.w = f2b(v.w);
    return o;
}

// ---------- constants ----------
#define MROWS 6272
#define CDIM  768
#define HID   3072
#define QKV3  2304

// ---------- fp32 -> bf16 cast (weights) ----------
__global__ __launch_bounds__(256) void cvt_f2b(const float4* __restrict__ in,
                                               ushort4* __restrict__ out, int n4){
    int i = blockIdx.x * 256 + threadIdx.x;
    if (i < n4) out[i] = cvt4(in[i]);
}

// ---------- window gather: x fp32 (B,197,C) -> win bf16 (128*49, C), shifted ----------
__global__ __launch_bounds__(256) void gather_win(const float4* __restrict__ x,
                                                  ushort4* __restrict__ win){
    int idx = blockIdx.x * 256 + threadIdx.x;           // over 6272*192 groups of 4
    if (idx >= MROWS * 192) return;
    int r  = idx / 192, c4 = idx % 192;
    int w  = r / 49,  t  = r % 49;
    int b  = w >> 2,  wi = w & 3;
    int wy = wi >> 1, wx = wi & 1;
    int ty = t / 7,   tx = t % 7;
    int ys = (wy*7 + ty + 3) % 14;                       // roll(-3)
    int xs = (wx*7 + tx + 3) % 14;
    win[idx] = cvt4(x[(size_t)b*197*192 + (size_t)(1 + ys*14 + xs)*192 + c4]);
}

// ---------- reverse: proj fp32 (window layout) -> f fp32 + fbf bf16 (spatial) ----------
__global__ __launch_bounds__(256) void scatter_f(const float4* __restrict__ proj,
                                                 float4* __restrict__ f,
                                                 ushort4* __restrict__ fbf){
    int idx = blockIdx.x * 256 + threadIdx.x;
    if (idx >= MROWS * 192) return;
    int r  = idx / 192, c4 = idx % 192;
    int w  = r / 49,  t  = r % 49;
    int b  = w >> 2,  wi = w & 3;
    int wy = wi >> 1, wx = wi & 1;
    int ty = t / 7,   tx = t % 7;
    int yd = (wy*7 + ty + 3) % 14;                       // roll(+3) inverse
    int xd = (wx*7 + tx + 3) % 14;
    float4 v = proj[idx];
    size_t off = (size_t)b*196*192 + (size_t)(yd*14 + xd)*192 + c4;
    f[off] = v;
    fbf[off] = cvt4(v);
}

// ---------- MFMA GEMM: C(MxN) = A(MxK) @ B(NxK)^T (+bias), bf16 in, fp32 acc ----------
__global__ __launch_bounds__(256) void gemm_bt(const ushort_t* __restrict__ A,
                                               const ushort_t* __restrict__ B,
                                               ushort_t* __restrict__ Cb,
                                               float* __restrict__ Cf,
                                               int M, int N, int K,
                                               const float* __restrict__ bias){
    __shared__ __align__(16) ushort_t As[128*32];
    __shared__ __align__(16) ushort_t Bs[128*32];
    const int tid  = threadIdx.x;
    const int lane = tid & 63;
    const int wid  = tid >> 6;
    const int m0 = blockIdx.y * 128;
    const int n0 = blockIdx.x * 128;
    const int wm = (wid >> 1) * 64;
    const int wn = (wid & 1) * 64;

    floatx4 acc[4][4] = {};

    for (int k0 = 0; k0 < K; k0 += 32){
        __syncthreads();
        #pragma unroll
        for (int j = 0; j < 2; ++j){
            int ch  = wid*2 + j;
            int row = ch*16 + (lane >> 2);
            int col = (lane & 3) * 8;
            const ushort_t* gA = A + (size_t)(m0 + row)*K + k0 + col;
            const ushort_t* gB = B + (size_t)(n0 + row)*K + k0 + col;
            __builtin_amdgcn_global_load_lds(
                (const __attribute__((address_space(1))) void*)gA,
                (__attribute__((address_space(3))) void*)(As + ch*512 + lane*8), 16, 0, 0);
            __builtin_amdgcn_global_load_lds(
                (const __attribute__((address_space(1))) void*)gB,
                (__attribute__((address_space(3))) void*)(Bs + ch*512 + lane*8), 16, 0, 0);
        }
        __syncthreads();

        short8 af[4], bfr[4];
        const int fr = lane & 15;
        const int co = (lane >> 4) * 8;
        #pragma unroll
        for (int i = 0; i < 4; ++i){
            af[i]  = *(const short8*)(As + (wm + i*16 + fr)*32 + co);
            bfr[i] = *(const short8*)(Bs + (wn + i*16 + fr)*32 + co);
        }
        #pragma unroll
        for (int i = 0; i < 4; ++i)
            #pragma unroll
            for (int j = 0; j < 4; ++j)
                acc[i][j] = __builtin_amdgcn_mfma_f32_16x16x32_bf16(af[i], bfr[j], acc[i][j], 0, 0, 0);
    }

    #pragma unroll
    for (int i = 0; i < 4; ++i){
        int grow = m0 + wm + i*16 + (lane >> 4)*4;
        #pragma unroll
        for (int j = 0; j < 4; ++j){
            int gcol = n0 + wn + j*16 + (lane & 15);
            float bv = bias ? bias[gcol] : 0.f;
            if (Cb){
                #pragma unroll
                for (int r = 0; r < 4; ++r)
                    Cb[(size_t)(grow + r)*N + gcol] = f2b(acc[i][j][r] + bv);
            } else {
                #pragma unroll
                for (int r = 0; r < 4; ++r)
                    Cf[(size_t)(grow + r)*N + gcol] = acc[i][j][r] + bv;
            }
        }
    }
}

// ---------- attention ----------
__global__ __launch_bounds__(256) void attn_kernel(const ushort_t* __restrict__ qkv,
                                                   ushort_t* __restrict__ outp,
                                                   const float* __restrict__ rpb){
    __shared__ float qs[49*65];
    __shared__ float ks[49*65];
    __shared__ float vs[49*65];
    __shared__ float Ss[49*50];
    __shared__ int   code[49];
    const int tid = threadIdx.x;
    const int h = blockIdx.x;
    const int w = blockIdx.y;
    const int wi = w & 3;
    const int wy = wi >> 1, wx = wi & 1;

    if (tid < 49){
        int ty = tid / 7, tx = tid % 7;
        int gy = wy*7 + ty, gx = wx*7 + tx;
        int ch = (gy < 7) ? 0 : (gy < 11 ? 1 : 2);
        int cw = (gx < 7) ? 0 : (gx < 11 ? 1 : 2);
        code[tid] = ch*3 + cw;
    }
    for (int idx = tid; idx < 49*64; idx += 256){
        int t = idx >> 6, d = idx & 63;
        size_t base = (size_t)(w*49 + t)*QKV3 + h*64 + d;
        qs[t*65 + d] = b2f(qkv[base]) * 0.125f;
        ks[t*65 + d] = b2f(qkv[base + 768]);
        vs[t*65 + d] = b2f(qkv[base + 1536]);
    }
    __syncthreads();

    for (int idx = tid; idx < 49*49; idx += 256){
        int qi = idx / 49, ki = idx - qi*49;
        const float* qr = qs + qi*65;
        const float* kr = ks + ki*65;
        float a = 0.f;
        #pragma unroll 8
        for (int d = 0; d < 64; ++d) a += qr[d]*kr[d];
        int qy = qi/7, qx = qi%7, ky = ki/7, kx = ki%7;
        int ridx = (qy - ky + 6)*13 + (qx - kx + 6);
        a += rpb[ridx*12 + h];
        if (code[qi] != code[ki]) a -= 100.f;
        Ss[qi*50 + ki] = a;
    }
    __syncthreads();

    if (tid < 49){
        float* row = Ss + tid*50;
        float m = row[0];
        for (int k = 1; k < 49; ++k) m = fmaxf(m, row[k]);
        float s = 0.f;
        for (int k = 0; k < 49; ++k){ float e = __expf(row[k] - m); row[k] = e; s += e; }
        float inv = 1.f / s;
        for (int k = 0; k < 49; ++k) row[k] *= inv;
    }
    __syncthreads();

    for (int idx = tid; idx < 49*64; idx += 256){
        int qi = idx >> 6, d = idx & 63;
        const float* sr = Ss + qi*50;
        const float* vc = vs + d;
        float a = 0.f;
        #pragma unroll 7
        for (int k = 0; k < 49; ++k) a += sr[k]*vc[k*65];
        outp[(size_t)(w*49 + qi)*CDIM + h*64 + d] = f2b(a);
    }
}

// ---------- BN ----------
__global__ void zero_f32(float* __restrict__ p, int n){
    int i = blockIdx.x*256 + threadIdx.x;
    if (i < n) p[i] = 0.f;
}
__global__ __launch_bounds__(256) void bn_stats(const ushort_t* __restrict__ X,
                                                float* __restrict__ sums, int Cch){
    int c  = blockIdx.x*256 + threadIdx.x;
    int r0 = blockIdx.y * 784;
    float s = 0.f, s2 = 0.f;
    for (int r = r0; r < r0 + 784; ++r){
        float v = b2f(X[(size_t)r*Cch + c]);
        s += v; s2 += v*v;
    }
    atomicAdd(&sums[c], s);
    atomicAdd(&sums[Cch + c], s2);
}
__global__ __launch_bounds__(256) void bn_stats_f(const float* __restrict__ X,
                                                  float* __restrict__ sums, int Cch){
    int c  = blockIdx.x*256 + threadIdx.x;
    int r0 = blockIdx.y * 784;
    float s = 0.f, s2 = 0.f;
    for (int r = r0; r < r0 + 784; ++r){
        float v = X[(size_t)r*Cch + c];
        s += v; s2 += v*v;
    }
    atomicAdd(&sums[c], s);
    atomicAdd(&sums[Cch + c], s2);
}
__global__ void bn_finalize(float* __restrict__ sums, const float* __restrict__ g,
                            const float* __restrict__ b, int Cch){
    int c = blockIdx.x*256 + threadIdx.x;
    if (c >= Cch) return;
    float mean = sums[c] * (1.f/6272.f);
    float var  = sums[Cch + c] * (1.f/6272.f) - mean*mean;
    float sc = g[c] * rsqrtf(var + 1e-5f);
    sums[c] = sc;
    sums[Cch + c] = b[c] - mean*sc;
}
__global__ __launch_bounds__(256) void bn_apply(ushort_t* __restrict__ X,
                                                const float* __restrict__ ss,
                                                int Cch, int total8, int act){
    int idx = blockIdx.x*256 + threadIdx.x;
    if (idx >= total8) return;
    int c8 = idx % (Cch/8);
    uint4 u = ((uint4*)X)[idx];
    float f[8]; unpack8(u, f);
    int cb = c8*8;
    #pragma unroll
    for (int e = 0; e < 8; ++e){
        float y = f[e]*ss[cb+e] + ss[Cch+cb+e];
        if (act) y = y * fminf(fmaxf(y + 3.f, 0.f), 6.f) * (1.f/6.f);
        f[e] = y;
    }
    ((uint4*)X)[idx] = pack8(f);
}

// ---------- depthwise 3x3 ----------
__global__ __launch_bounds__(256) void dwconv(const ushort_t* __restrict__ in,
                                              const float* __restrict__ wgt,
                                              ushort_t* __restrict__ out){
    int blk = blockIdx.x;
    int b = blk / 196, p = blk % 196;
    int y = p / 14, x = p % 14;
    const size_t base = (size_t)b * 196 * HID;
    for (int c = threadIdx.x; c < HID; c += 256){
        float a = 0.f;
        #pragma unroll
        for (int i = 0; i < 3; ++i){
            int yy = y + i - 1;
            if (yy < 0 || yy >= 14) continue;
            #pragma unroll
            for (int j = 0; j < 3; ++j){
                int xx = x + j - 1;
                if (xx < 0 || xx >= 14) continue;
                a += b2f(in[base + (size_t)(yy*14 + xx)*HID + c]) * wgt[c*9 + i*3 + j];
            }
        }
        out[base + (size_t)p*HID + c] = f2b(a);
    }
}

// ---------- SE ----------
__global__ __launch_bounds__(256) void se_mean(const ushort_t* __restrict__ X,
                                               float* __restrict__ s){
    int b = blockIdx.x;
    int c = blockIdx.y*256 + threadIdx.x;
    float a = 0.f;
    for (int p = 0; p < 196; ++p)
        a += b2f(X[((size_t)b*196 + p)*HID + c]);
    s[b*HID + c] = a * (1.f/196.f);
}
// FC for all 32 batches at once: one WAVE per output channel n.
// Lanes stride K (coalesced w-row read, each weight read once);
// 32 per-batch accumulators/lane; 32 shuffle reductions at the end.
__global__ __launch_bounds__(256) void se_fc(const float* __restrict__ in,
                                             const float* __restrict__ w,
                                             const float* __restrict__ bias,
                                             float* __restrict__ out,
                                             int IN, int OUT, int mode){
    int wv   = (blockIdx.x*256 + threadIdx.x) >> 6;   // global wave id = n
    int lane = threadIdx.x & 63;
    if (wv >= OUT) return;
    const float* wr = w + (size_t)wv * IN;
    float acc[32];
    #pragma unroll
    for (int b = 0; b < 32; ++b) acc[b] = 0.f;
    for (int k = lane; k < IN; k += 64){
        float wval = wr[k];
        #pragma unroll
        for (int b = 0; b < 32; ++b)
            acc[b] += in[b*IN + k] * wval;
    }
    #pragma unroll
    for (int b = 0; b < 32; ++b){
        float v = acc[b];
        #pragma unroll
        for (int off = 32; off; off >>= 1) v += __shfl_down(v, off, 64);
        if (lane == 0){
            float a = v + bias[wv];
            if (mode == 0) a = fmaxf(a, 0.f);
            else           a = fminf(fmaxf(a + 3.f, 0.f), 6.f) * (1.f/6.f);
            out[b*OUT + wv] = a;
        }
    }
}
__global__ __launch_bounds__(256) void se_scale(ushort_t* __restrict__ X,
                                                const float* __restrict__ s2){
    int idx = blockIdx.x*256 + threadIdx.x;
    if (idx >= MROWS * (HID/8)) return;
    int r = idx / (HID/8), c8 = idx % (HID/8);
    int b = r / 196;
    uint4 u = ((uint4*)X)[idx];
    float f[8]; unpack8(u, f);
    const float* sp = s2 + b*HID + c8*8;
    #pragma unroll
    for (int e = 0; e < 8; ++e) f[e] *= sp[e];
    ((uint4*)X)[idx] = pack8(f);
}

// ---------- final ----------
__global__ __launch_bounds__(256) void final_k(const float4* __restrict__ xin,
                                               const float4* __restrict__ f,
                                               const float4* __restrict__ h4,
                                               const float* __restrict__ ss,
                                               float4* __restrict__ outp){
    int idx = blockIdx.x*256 + threadIdx.x;
    if (idx >= 32*197*192) return;
    int b = idx / (197*192);
    int rem = idx % (197*192);
    int n = rem / 192, c4 = rem % 192;
    if (n == 0){ outp[idx] = xin[idx]; return; }
    size_t off = ((size_t)b*196 + n - 1)*192 + c4;
    float4 hv = h4[off];
    float4 fv = f[off];
    float4 o;
    int c = c4*4;
    o.x = fv.x + hv.x*ss[c+0] + ss[CDIM + c+0];
    o.y = fv.y + hv.y*ss[c+1] + ss[CDIM + c+1];
    o.z = fv.z + hv.z*ss[c+2] + ss[CDIM + c+2];
    o.w = fv.w + hv.w*ss[c+3] + ss[CDIM + c+3];
    outp[idx] = o;
}

extern "C" void kernel_launch(void* const* d_in, const int* in_sizes, int n_in,
                              void* d_out, int out_size, void* d_ws, size_t ws_size,
                              hipStream_t stream){
    const float* x      = (const float*)d_in[0];
    const float* w_qkv  = (const float*)d_in[1];
    const float* w_proj = (const float*)d_in[2];
    const float* b_proj = (const float*)d_in[3];
    const float* rpb    = (const float*)d_in[4];
    const float* pw1_w  = (const float*)d_in[5];
    const float* bn1_g  = (const float*)d_in[6];
    const float* bn1_b  = (const float*)d_in[7];
    const float* dw_w   = (const float*)d_in[8];
    const float* bn2_g  = (const float*)d_in[9];
    const float* bn2_b  = (const float*)d_in[10];
    const float* se_w1  = (const float*)d_in[11];
    const float* se_b1  = (const float*)d_in[12];
    const float* se_w2  = (const float*)d_in[13];
    const float* se_b2  = (const float*)d_in[14];
    const float* pw2_w  = (const float*)d_in[15];
    const float* bn3_g  = (const float*)d_in[16];
    const float* bn3_b  = (const float*)d_in[17];

    char* ws = (char*)d_ws;
    ushort_t* win    = (ushort_t*)(ws + 0);
    ushort_t* qkv    = (ushort_t*)(ws + 9633792);
    ushort_t* ha     = (ushort_t*)(ws + 0);
    float*    h4     = (float*)(ws + 0);
    ushort_t* pw2b   = (ushort_t*)(ws + 19267584);
    ushort_t* attnb  = (ushort_t*)(ws + 38535168);
    ushort_t* fbf    = (ushort_t*)(ws + 38535168);
    float*    proj   = (float*)(ws + 48168960);
    ushort_t* pw1b   = (ushort_t*)(ws + 67436544);
    ushort_t* hb     = (ushort_t*)(ws + 38535168);
    ushort_t* wqkvb  = (ushort_t*)(ws + 77070336);
    ushort_t* wprojb = (ushort_t*)(ws + 80609280);
    float*    f      = (float*)(ws + 77070336);
    float*    stats  = (float*)(ws + 96337920);
    float*    s      = (float*)(ws + 96362496);
    float*    s1     = (float*)(ws + 96755712);
    float*    s2     = (float*)(ws + 96854016);

    const int vec_rows = (MROWS*192 + 255)/256;
    const int vec_hid8 = (MROWS*(HID/8) + 255)/256;

    cvt_f2b<<<(QKV3*CDIM/4 + 255)/256, 256, 0, stream>>>((const float4*)w_qkv, (ushort4*)wqkvb, QKV3*CDIM/4);
    cvt_f2b<<<(CDIM*CDIM/4 + 255)/256, 256, 0, stream>>>((const float4*)w_proj, (ushort4*)wprojb, CDIM*CDIM/4);
    cvt_f2b<<<(HID*CDIM/4 + 255)/256, 256, 0, stream>>>((const float4*)pw1_w, (ushort4*)pw1b, HID*CDIM/4);

    gather_win<<<vec_rows, 256, 0, stream>>>((const float4*)x, (ushort4*)win);
    gemm_bt<<<dim3(QKV3/128, MROWS/128), 256, 0, stream>>>(win, wqkvb, qkv, nullptr, MROWS, QKV3, CDIM, nullptr);
    attn_kernel<<<dim3(12, 128), 256, 0, stream>>>(qkv, attnb, rpb);
    gemm_bt<<<dim3(CDIM/128, MROWS/128), 256, 0, stream>>>(attnb, wprojb, nullptr, proj, MROWS, CDIM, CDIM, b_proj);
    scatter_f<<<vec_rows, 256, 0, stream>>>((const float4*)proj, (float4*)f, (ushort4*)fbf);

    gemm_bt<<<dim3(HID/128, MROWS/128), 256, 0, stream>>>(fbf, pw1b, ha, nullptr, MROWS, HID, CDIM, nullptr);
    zero_f32<<<24, 256, 0, stream>>>(stats, 2*HID);
    bn_stats<<<dim3(HID/256, 8), 256, 0, stream>>>(ha, stats, HID);
    bn_finalize<<<HID/256, 256, 0, stream>>>(stats, bn1_g, bn1_b, HID);
    bn_apply<<<vec_hid8, 256, 0, stream>>>(ha, stats, HID, MROWS*(HID/8), 1);

    dwconv<<<MROWS, 256, 0, stream>>>(ha, dw_w, hb);
    cvt_f2b<<<(CDIM*HID/4 + 255)/256, 256, 0, stream>>>((const float4*)pw2_w, (ushort4*)pw2b, CDIM*HID/4);
    zero_f32<<<24, 256, 0, stream>>>(stats, 2*HID);
    bn_stats<<<dim3(HID/256, 8), 256, 0, stream>>>(hb, stats, HID);
    bn_finalize<<<HID/256, 256, 0, stream>>>(stats, bn2_g, bn2_b, HID);
    bn_apply<<<vec_hid8, 256, 0, stream>>>(hb, stats, HID, MROWS*(HID/8), 1);

    se_mean<<<dim3(32, HID/256), 256, 0, stream>>>(hb, s);
    se_fc<<<dim3((CDIM*64 + 255)/256), 256, 0, stream>>>(s, se_w1, se_b1, s1, HID, CDIM, 0);
    se_fc<<<dim3((HID*64 + 255)/256), 256, 0, stream>>>(s1, se_w2, se_b2, s2, CDIM, HID, 1);
    se_scale<<<vec_hid8, 256, 0, stream>>>(hb, s2);

    gemm_bt<<<dim3(CDIM/128, MROWS/128), 256, 0, stream>>>(hb, pw2b, nullptr, h4, MROWS, CDIM, HID, nullptr);
    zero_f32<<<6, 256, 0, stream>>>(stats, 2*CDIM);
    bn_stats_f<<<dim3(CDIM/256, 8), 256, 0, stream>>>(h4, stats, CDIM);
    bn_finalize<<<CDIM/256, 256, 0, stream>>>(stats, bn3_g, bn3_b, CDIM);
    final_k<<<(32*197*192 + 255)/256, 256, 0, stream>>>((const float4*)x, (const float4*)f, (const float4*)h4, stats, (float4*)d_out);
}

// Round 5
// 721.964 us; speedup vs baseline: 1.8024x; 1.3390x over previous
//
#include <hip/hip_runtime.h>
#include <hip/hip_bf16.h>

typedef unsigned short ushort_t;
typedef unsigned int uint_t;
typedef short short8 __attribute__((ext_vector_type(8)));
typedef float floatx4 __attribute__((ext_vector_type(4)));

// ---------- bf16 helpers (raw ushort storage) ----------
__device__ inline float b2f(ushort_t u){
    uint_t v = ((uint_t)u) << 16;
    return __uint_as_float(v);
}
__device__ inline ushort_t f2b(float f){
    uint_t v = __float_as_uint(f);
    uint_t r = (v + 0x7FFFu + ((v >> 16) & 1u)) >> 16;  // RNE
    return (ushort_t)r;
}
__device__ inline void unpack8(uint4 u, float* f){
    uint_t w[4] = {u.x, u.y, u.z, u.w};
    #pragma unroll
    for (int i = 0; i < 4; ++i){
        f[2*i]   = __uint_as_float(w[i] << 16);
        f[2*i+1] = __uint_as_float(w[i] & 0xFFFF0000u);
    }
}
__device__ inline uint4 pack8(const float* f){
    uint4 o;
    uint_t w[4];
    #pragma unroll
    for (int i = 0; i < 4; ++i)
        w[i] = (uint_t)f2b(f[2*i]) | ((uint_t)f2b(f[2*i+1]) << 16);
    o.x = w[0]; o.y = w[1]; o.z = w[2]; o.w = w[3];
    return o;
}
__device__ inline ushort4 cvt4(float4 v){
    ushort4 o;
    o.x = f2b(v.x); o.y = f2b(v.y); o.z = f2b(v.z); o.w = f2b(v.w);
    return o;
}

// ---------- constants ----------
#define MROWS 6272
#define CDIM  768
#define HID   3072
#define QKV3  2304

// swin window->spatial row map (with +3 roll): ri (window layout) -> dest row (b*196+p)
__device__ inline int scatter_row(int ri){
    int w  = ri / 49, t = ri % 49;
    int b  = w >> 2,  wi = w & 3;
    int wy = wi >> 1, wx = wi & 1;
    int ty = t / 7,   tx = t % 7;
    int yd = (wy*7 + ty + 3) % 14;
    int xd = (wx*7 + tx + 3) % 14;
    return b*196 + yd*14 + xd;
}

// ---------- fp32 -> bf16 cast (weights) ----------
__global__ __launch_bounds__(256) void cvt_f2b(const float4* __restrict__ in,
                                               ushort4* __restrict__ out, int n4){
    int i = blockIdx.x * 256 + threadIdx.x;
    if (i < n4) out[i] = cvt4(in[i]);
}

// ---------- dw weight transpose: [3072][9] -> [9][3072] ----------
__global__ __launch_bounds__(256) void dw_transpose(const float* __restrict__ w,
                                                    float* __restrict__ wT){
    int i = blockIdx.x*256 + threadIdx.x;
    if (i < HID*9){ int c = i/9, k = i%9; wT[k*HID + c] = w[i]; }
}

// ---------- window gather: x fp32 (B,197,C) -> win bf16 (128*49, C), shifted ----------
__global__ __launch_bounds__(256) void gather_win(const float4* __restrict__ x,
                                                  ushort4* __restrict__ win){
    int idx = blockIdx.x * 256 + threadIdx.x;
    if (idx >= MROWS * 192) return;
    int r  = idx / 192, c4 = idx % 192;
    int w  = r / 49,  t  = r % 49;
    int b  = w >> 2,  wi = w & 3;
    int wy = wi >> 1, wx = wi & 1;
    int ty = t / 7,   tx = t % 7;
    int ys = (wy*7 + ty + 3) % 14;                       // roll(-3)
    int xs = (wx*7 + tx + 3) % 14;
    win[idx] = cvt4(x[(size_t)b*197*192 + (size_t)(1 + ys*14 + xs)*192 + c4]);
}

// ---------- MFMA GEMM: C(MxN) = A(MxK) @ B(NxK)^T (+bias), bf16 in, fp32 acc ----------
// scat=0: write Cb (bf16) if non-null else Cf (fp32), row = m.
// scat=1: dual write Cf fp32 + Cb bf16 at scatter_row(m) (swin reverse shift).
// stats!=null: atomicAdd per-column sum/sumsq (BN over M) into stats[0..N),[N..2N).
__global__ __launch_bounds__(256) void gemm_bt(const ushort_t* __restrict__ A,
                                               const ushort_t* __restrict__ B,
                                               ushort_t* __restrict__ Cb,
                                               float* __restrict__ Cf,
                                               int M, int N, int K,
                                               const float* __restrict__ bias,
                                               float* __restrict__ stats,
                                               int scat){
    __shared__ __align__(16) ushort_t As[128*32];
    __shared__ __align__(16) ushort_t Bs[128*32];
    const int tid  = threadIdx.x;
    const int lane = tid & 63;
    const int wid  = tid >> 6;
    const int m0 = blockIdx.y * 128;
    const int n0 = blockIdx.x * 128;
    const int wm = (wid >> 1) * 64;
    const int wn = (wid & 1) * 64;

    floatx4 acc[4][4] = {};

    for (int k0 = 0; k0 < K; k0 += 32){
        __syncthreads();
        #pragma unroll
        for (int j = 0; j < 2; ++j){
            int ch  = wid*2 + j;
            int row = ch*16 + (lane >> 2);
            int col = (lane & 3) * 8;
            const ushort_t* gA = A + (size_t)(m0 + row)*K + k0 + col;
            const ushort_t* gB = B + (size_t)(n0 + row)*K + k0 + col;
            __builtin_amdgcn_global_load_lds(
                (const __attribute__((address_space(1))) void*)gA,
                (__attribute__((address_space(3))) void*)(As + ch*512 + lane*8), 16, 0, 0);
            __builtin_amdgcn_global_load_lds(
                (const __attribute__((address_space(1))) void*)gB,
                (__attribute__((address_space(3))) void*)(Bs + ch*512 + lane*8), 16, 0, 0);
        }
        __syncthreads();

        short8 af[4], bfr[4];
        const int fr = lane & 15;
        const int co = (lane >> 4) * 8;
        #pragma unroll
        for (int i = 0; i < 4; ++i){
            af[i]  = *(const short8*)(As + (wm + i*16 + fr)*32 + co);
            bfr[i] = *(const short8*)(Bs + (wn + i*16 + fr)*32 + co);
        }
        #pragma unroll
        for (int i = 0; i < 4; ++i)
            #pragma unroll
            for (int j = 0; j < 4; ++j)
                acc[i][j] = __builtin_amdgcn_mfma_f32_16x16x32_bf16(af[i], bfr[j], acc[i][j], 0, 0, 0);
    }

    // epilogue: C/D layout col=lane&15, row=(lane>>4)*4+r  [m89-verified]
    #pragma unroll
    for (int i = 0; i < 4; ++i){
        int grow = m0 + wm + i*16 + (lane >> 4)*4;
        #pragma unroll
        for (int j = 0; j < 4; ++j){
            int gcol = n0 + wn + j*16 + (lane & 15);
            float bv = bias ? bias[gcol] : 0.f;
            if (scat){
                #pragma unroll
                for (int r = 0; r < 4; ++r){
                    float v = acc[i][j][r] + bv;
                    size_t off = (size_t)scatter_row(grow + r)*N + gcol;
                    Cf[off] = v;
                    Cb[off] = f2b(v);
                }
            } else if (Cb){
                #pragma unroll
                for (int r = 0; r < 4; ++r)
                    Cb[(size_t)(grow + r)*N + gcol] = f2b(acc[i][j][r] + bv);
            } else {
                #pragma unroll
                for (int r = 0; r < 4; ++r)
                    Cf[(size_t)(grow + r)*N + gcol] = acc[i][j][r] + bv;
            }
        }
    }

    if (stats){
        // per-column (over M) sum / sumsq for batch-norm, fused.
        #pragma unroll
        for (int j = 0; j < 4; ++j){
            int gcol = n0 + wn + j*16 + (lane & 15);
            float bv = bias ? bias[gcol] : 0.f;
            float sv = 0.f, sq = 0.f;
            #pragma unroll
            for (int i = 0; i < 4; ++i)
                #pragma unroll
                for (int r = 0; r < 4; ++r){
                    float v = acc[i][j][r] + bv;
                    sv += v; sq += v*v;
                }
            sv += __shfl_xor(sv, 16, 64);  sq += __shfl_xor(sq, 16, 64);
            sv += __shfl_xor(sv, 32, 64);  sq += __shfl_xor(sq, 32, 64);
            if (lane < 16){
                atomicAdd(&stats[gcol], sv);
                atomicAdd(&stats[N + gcol], sq);
            }
        }
    }
}

// ---------- attention ----------
__global__ __launch_bounds__(256) void attn_kernel(const ushort_t* __restrict__ qkv,
                                                   ushort_t* __restrict__ outp,
                                                   const float* __restrict__ rpb){
    __shared__ float qs[49*65];
    __shared__ float ks[49*65];
    __shared__ float vs[49*65];
    __shared__ float Ss[49*50];
    __shared__ int   code[49];
    const int tid = threadIdx.x;
    const int h = blockIdx.x;
    const int w = blockIdx.y;
    const int wi = w & 3;
    const int wy = wi >> 1, wx = wi & 1;

    if (tid < 49){
        int ty = tid / 7, tx = tid % 7;
        int gy = wy*7 + ty, gx = wx*7 + tx;
        int ch = (gy < 7) ? 0 : (gy < 11 ? 1 : 2);
        int cw = (gx < 7) ? 0 : (gx < 11 ? 1 : 2);
        code[tid] = ch*3 + cw;
    }
    for (int idx = tid; idx < 49*64; idx += 256){
        int t = idx >> 6, d = idx & 63;
        size_t base = (size_t)(w*49 + t)*QKV3 + h*64 + d;
        qs[t*65 + d] = b2f(qkv[base]) * 0.125f;
        ks[t*65 + d] = b2f(qkv[base + 768]);
        vs[t*65 + d] = b2f(qkv[base + 1536]);
    }
    __syncthreads();

    for (int idx = tid; idx < 49*49; idx += 256){
        int qi = idx / 49, ki = idx - qi*49;
        const float* qr = qs + qi*65;
        const float* kr = ks + ki*65;
        float a = 0.f;
        #pragma unroll 8
        for (int d = 0; d < 64; ++d) a += qr[d]*kr[d];
        int qy = qi/7, qx = qi%7, ky = ki/7, kx = ki%7;
        int ridx = (qy - ky + 6)*13 + (qx - kx + 6);
        a += rpb[ridx*12 + h];
        if (code[qi] != code[ki]) a -= 100.f;
        Ss[qi*50 + ki] = a;
    }
    __syncthreads();

    if (tid < 49){
        float* row = Ss + tid*50;
        float m = row[0];
        for (int k = 1; k < 49; ++k) m = fmaxf(m, row[k]);
        float s = 0.f;
        for (int k = 0; k < 49; ++k){ float e = __expf(row[k] - m); row[k] = e; s += e; }
        float inv = 1.f / s;
        for (int k = 0; k < 49; ++k) row[k] *= inv;
    }
    __syncthreads();

    for (int idx = tid; idx < 49*64; idx += 256){
        int qi = idx >> 6, d = idx & 63;
        const float* sr = Ss + qi*50;
        const float* vc = vs + d;
        float a = 0.f;
        #pragma unroll 7
        for (int k = 0; k < 49; ++k) a += sr[k]*vc[k*65];
        outp[(size_t)(w*49 + qi)*CDIM + h*64 + d] = f2b(a);
    }
}

// ---------- BN ----------
__global__ void zero_f32(float* __restrict__ p, int n){
    int i = blockIdx.x*256 + threadIdx.x;
    if (i < n) p[i] = 0.f;
}
__global__ __launch_bounds__(256) void bn_stats(const ushort_t* __restrict__ X,
                                                float* __restrict__ sums, int Cch){
    int c  = blockIdx.x*256 + threadIdx.x;
    int r0 = blockIdx.y * 784;
    float s = 0.f, s2 = 0.f;
    for (int r = r0; r < r0 + 784; ++r){
        float v = b2f(X[(size_t)r*Cch + c]);
        s += v; s2 += v*v;
    }
    atomicAdd(&sums[c], s);
    atomicAdd(&sums[Cch + c], s2);
}
__global__ void bn_finalize(float* __restrict__ sums, const float* __restrict__ g,
                            const float* __restrict__ b, int Cch){
    int c = blockIdx.x*256 + threadIdx.x;
    if (c >= Cch) return;
    float mean = sums[c] * (1.f/6272.f);
    float var  = sums[Cch + c] * (1.f/6272.f) - mean*mean;
    float sc = g[c] * rsqrtf(var + 1e-5f);
    sums[c] = sc;
    sums[Cch + c] = b[c] - mean*sc;
}
__global__ __launch_bounds__(256) void bn_apply(ushort_t* __restrict__ X,
                                                const float* __restrict__ ss,
                                                int Cch, int total8, int act){
    int idx = blockIdx.x*256 + threadIdx.x;
    if (idx >= total8) return;
    int c8 = idx % (Cch/8);
    uint4 u = ((uint4*)X)[idx];
    float f[8]; unpack8(u, f);
    int cb = c8*8;
    #pragma unroll
    for (int e = 0; e < 8; ++e){
        float y = f[e]*ss[cb+e] + ss[Cch+cb+e];
        if (act) y = y * fminf(fmaxf(y + 3.f, 0.f), 6.f) * (1.f/6.f);
        f[e] = y;
    }
    ((uint4*)X)[idx] = pack8(f);
}

// ---------- depthwise 3x3, vectorized: 1 thread = 8 channels @ 1 pixel ----------
__global__ __launch_bounds__(256) void dwconv_v(const ushort_t* __restrict__ in,
                                                const float* __restrict__ wT,
                                                ushort_t* __restrict__ out){
    int idx = blockIdx.x*256 + threadIdx.x;      // over MROWS*384
    if (idx >= MROWS*384) return;
    int r  = idx / 384, cg = idx % 384;          // lanes: consecutive cg -> coalesced
    int b  = r / 196,  p  = r % 196;
    int y  = p / 14,   x  = p % 14;
    int c  = cg*8;
    const uint4* inb = (const uint4*)(in + (size_t)b*196*HID);
    float acc[8] = {};
    #pragma unroll
    for (int ky = 0; ky < 3; ++ky){
        int yy = y + ky - 1;
        if ((unsigned)yy >= 14u) continue;
        #pragma unroll
        for (int kx = 0; kx < 3; ++kx){
            int xx = x + kx - 1;
            if ((unsigned)xx >= 14u) continue;
            uint4 u = inb[(yy*14 + xx)*384 + cg];
            float fin[8]; unpack8(u, fin);
            const float4* wp = (const float4*)(wT + (ky*3 + kx)*HID + c);
            float4 w0 = wp[0], w1 = wp[1];
            acc[0] += fin[0]*w0.x; acc[1] += fin[1]*w0.y;
            acc[2] += fin[2]*w0.z; acc[3] += fin[3]*w0.w;
            acc[4] += fin[4]*w1.x; acc[5] += fin[5]*w1.y;
            acc[6] += fin[6]*w1.z; acc[7] += fin[7]*w1.w;
        }
    }
    ((uint4*)out)[idx] = pack8(acc);
}

// ---------- SE ----------
__global__ __launch_bounds__(256) void se_mean(const ushort_t* __restrict__ X,
                                               float* __restrict__ s){
    int b = blockIdx.x;
    int c = blockIdx.y*256 + threadIdx.x;
    float a = 0.f;
    for (int p = 0; p < 196; ++p)
        a += b2f(X[((size_t)b*196 + p)*HID + c]);
    s[b*HID + c] = a * (1.f/196.f);
}
__global__ __launch_bounds__(256) void se_fc(const float* __restrict__ in,
                                             const float* __restrict__ w,
                                             const float* __restrict__ bias,
                                             float* __restrict__ out,
                                             int IN, int OUT, int mode){
    int wv   = (blockIdx.x*256 + threadIdx.x) >> 6;
    int lane = threadIdx.x & 63;
    if (wv >= OUT) return;
    const float* wr = w + (size_t)wv * IN;
    float acc[32];
    #pragma unroll
    for (int b = 0; b < 32; ++b) acc[b] = 0.f;
    for (int k = lane; k < IN; k += 64){
        float wval = wr[k];
        #pragma unroll
        for (int b = 0; b < 32; ++b)
            acc[b] += in[b*IN + k] * wval;
    }
    #pragma unroll
    for (int b = 0; b < 32; ++b){
        float v = acc[b];
        #pragma unroll
        for (int off = 32; off; off >>= 1) v += __shfl_down(v, off, 64);
        if (lane == 0){
            float a = v + bias[wv];
            if (mode == 0) a = fmaxf(a, 0.f);
            else           a = fminf(fmaxf(a + 3.f, 0.f), 6.f) * (1.f/6.f);
            out[b*OUT + wv] = a;
        }
    }
}
__global__ __launch_bounds__(256) void se_scale(ushort_t* __restrict__ X,
                                                const float* __restrict__ s2){
    int idx = blockIdx.x*256 + threadIdx.x;
    if (idx >= MROWS * (HID/8)) return;
    int r = idx / (HID/8), c8 = idx % (HID/8);
    int b = r / 196;
    uint4 u = ((uint4*)X)[idx];
    float f[8]; unpack8(u, f);
    const float* sp = s2 + b*HID + c8*8;
    #pragma unroll
    for (int e = 0; e < 8; ++e) f[e] *= sp[e];
    ((uint4*)X)[idx] = pack8(f);
}

// ---------- final ----------
__global__ __launch_bounds__(256) void final_k(const float4* __restrict__ xin,
                                               const float4* __restrict__ f,
                                               const float4* __restrict__ h4,
                                               const float* __restrict__ ss,
                                               float4* __restrict__ outp){
    int idx = blockIdx.x*256 + threadIdx.x;
    if (idx >= 32*197*192) return;
    int b = idx / (197*192);
    int rem = idx % (197*192);
    int n = rem / 192, c4 = rem % 192;
    if (n == 0){ outp[idx] = xin[idx]; return; }
    size_t off = ((size_t)b*196 + n - 1)*192 + c4;
    float4 hv = h4[off];
    float4 fv = f[off];
    float4 o;
    int c = c4*4;
    o.x = fv.x + hv.x*ss[c+0] + ss[CDIM + c+0];
    o.y = fv.y + hv.y*ss[c+1] + ss[CDIM + c+1];
    o.z = fv.z + hv.z*ss[c+2] + ss[CDIM + c+2];
    o.w = fv.w + hv.w*ss[c+3] + ss[CDIM + c+3];
    outp[idx] = o;
}

extern "C" void kernel_launch(void* const* d_in, const int* in_sizes, int n_in,
                              void* d_out, int out_size, void* d_ws, size_t ws_size,
                              hipStream_t stream){
    const float* x      = (const float*)d_in[0];
    const float* w_qkv  = (const float*)d_in[1];
    const float* w_proj = (const float*)d_in[2];
    const float* b_proj = (const float*)d_in[3];
    const float* rpb    = (const float*)d_in[4];
    const float* pw1_w  = (const float*)d_in[5];
    const float* bn1_g  = (const float*)d_in[6];
    const float* bn1_b  = (const float*)d_in[7];
    const float* dw_w   = (const float*)d_in[8];
    const float* bn2_g  = (const float*)d_in[9];
    const float* bn2_b  = (const float*)d_in[10];
    const float* se_w1  = (const float*)d_in[11];
    const float* se_b1  = (const float*)d_in[12];
    const float* se_w2  = (const float*)d_in[13];
    const float* se_b2  = (const float*)d_in[14];
    const float* pw2_w  = (const float*)d_in[15];
    const float* bn3_g  = (const float*)d_in[16];
    const float* bn3_b  = (const float*)d_in[17];

    char* ws = (char*)d_ws;
    // lifetime-overlaid layout (bytes), peak 97,247,232 (same as round 3/4):
    //  R1 [0, 38535168):   win[0,9.6M)+qkv[9.6M,38.5M)  ->  fbf[0,9.6M)+pw1b[9.6M,14.35M)  ->  hb (full)
    //  R2 [38535168, 77070336): wqkvb[38.5M,..)/attnb[38.5M,48.2M)+wprojb[48.2M,49.3M)  ->  ha (full)
    //                        ->  h4 fp32 [38.5M,57.8M) + pw2b [57.8M,62.5M)
    //  R3 [77070336, 96337920): f fp32 (proj-gemm scatter output, lives to final_k)
    //  [96337920, 97247232): stats + s + s1 + s2; dwwT aliases s2 (dead before s2 written)
    ushort_t* win    = (ushort_t*)(ws + 0);
    ushort_t* qkv    = (ushort_t*)(ws + 9633792);
    ushort_t* fbf    = (ushort_t*)(ws + 0);
    ushort_t* pw1b   = (ushort_t*)(ws + 9633792);
    ushort_t* hb     = (ushort_t*)(ws + 0);
    ushort_t* wqkvb  = (ushort_t*)(ws + 38535168);
    ushort_t* attnb  = (ushort_t*)(ws + 38535168);
    ushort_t* wprojb = (ushort_t*)(ws + 48168960);
    ushort_t* ha     = (ushort_t*)(ws + 38535168);
    float*    h4     = (float*)(ws + 38535168);
    ushort_t* pw2b   = (ushort_t*)(ws + 57802752);
    float*    f      = (float*)(ws + 77070336);
    float*    stats  = (float*)(ws + 96337920);
    float*    s      = (float*)(ws + 96362496);
    float*    s1     = (float*)(ws + 96755712);
    float*    s2     = (float*)(ws + 96854016);
    float*    dwwT   = (float*)(ws + 96854016);   // alias s2: dead before se_fc writes s2

    const int vec_rows = (MROWS*192 + 255)/256;
    const int vec_hid8 = (MROWS*(HID/8) + 255)/256;

    // early weight prep (regions free at this point)
    dw_transpose<<<(HID*9 + 255)/256, 256, 0, stream>>>(dw_w, dwwT);
    cvt_f2b<<<(QKV3*CDIM/4 + 255)/256, 256, 0, stream>>>((const float4*)w_qkv, (ushort4*)wqkvb, QKV3*CDIM/4);
    cvt_f2b<<<(CDIM*CDIM/4 + 255)/256, 256, 0, stream>>>((const float4*)w_proj, (ushort4*)wprojb, CDIM*CDIM/4);

    // attention half
    gather_win<<<vec_rows, 256, 0, stream>>>((const float4*)x, (ushort4*)win);
    gemm_bt<<<dim3(QKV3/128, MROWS/128), 256, 0, stream>>>(win, wqkvb, qkv, nullptr, MROWS, QKV3, CDIM, nullptr, nullptr, 0);
    attn_kernel<<<dim3(12, 128), 256, 0, stream>>>(qkv, attnb, rpb);
    cvt_f2b<<<(HID*CDIM/4 + 255)/256, 256, 0, stream>>>((const float4*)pw1_w, (ushort4*)pw1b, HID*CDIM/4);  // qkv dead
    zero_f32<<<24, 256, 0, stream>>>(stats, 2*HID);   // for fused bn1 stats
    // proj GEMM with fused reverse-shift scatter: writes f (fp32) + fbf (bf16)
    gemm_bt<<<dim3(CDIM/128, MROWS/128), 256, 0, stream>>>(attnb, wprojb, fbf, f, MROWS, CDIM, CDIM, b_proj, nullptr, 1);

    // ConvFFN half
    gemm_bt<<<dim3(HID/128, MROWS/128), 256, 0, stream>>>(fbf, pw1b, ha, nullptr, MROWS, HID, CDIM, nullptr, stats, 0);
    bn_finalize<<<HID/256, 256, 0, stream>>>(stats, bn1_g, bn1_b, HID);
    bn_apply<<<vec_hid8, 256, 0, stream>>>(ha, stats, HID, MROWS*(HID/8), 1);

    dwconv_v<<<(MROWS*384 + 255)/256, 256, 0, stream>>>(ha, dwwT, hb);
    cvt_f2b<<<(CDIM*HID/4 + 255)/256, 256, 0, stream>>>((const float4*)pw2_w, (ushort4*)pw2b, CDIM*HID/4);  // ha dead
    zero_f32<<<24, 256, 0, stream>>>(stats, 2*HID);
    bn_stats<<<dim3(HID/256, 8), 256, 0, stream>>>(hb, stats, HID);
    bn_finalize<<<HID/256, 256, 0, stream>>>(stats, bn2_g, bn2_b, HID);
    bn_apply<<<vec_hid8, 256, 0, stream>>>(hb, stats, HID, MROWS*(HID/8), 1);

    se_mean<<<dim3(32, HID/256), 256, 0, stream>>>(hb, s);
    se_fc<<<dim3((CDIM*64)/256), 256, 0, stream>>>(s, se_w1, se_b1, s1, HID, CDIM, 0);
    se_fc<<<dim3((HID*64)/256), 256, 0, stream>>>(s1, se_w2, se_b2, s2, CDIM, HID, 1);
    se_scale<<<vec_hid8, 256, 0, stream>>>(hb, s2);

    zero_f32<<<6, 256, 0, stream>>>(stats, 2*CDIM);   // for fused bn3 stats
    gemm_bt<<<dim3(CDIM/128, MROWS/128), 256, 0, stream>>>(hb, pw2b, nullptr, h4, MROWS, CDIM, HID, nullptr, stats, 0);
    bn_finalize<<<CDIM/256, 256, 0, stream>>>(stats, bn3_g, bn3_b, CDIM);
    final_k<<<(32*197*192 + 255)/256, 256, 0, stream>>>((const float4*)x, (const float4*)f, (const float4*)h4, stats, (float4*)d_out);
}

// Round 6
// 685.790 us; speedup vs baseline: 1.8975x; 1.0527x over previous
//
#include <hip/hip_runtime.h>
#include <hip/hip_bf16.h>

typedef unsigned short ushort_t;
typedef unsigned int uint_t;
typedef short short8 __attribute__((ext_vector_type(8)));
typedef float floatx4 __attribute__((ext_vector_type(4)));

// ---------- bf16 helpers (raw ushort storage) ----------
__device__ inline float b2f(ushort_t u){
    uint_t v = ((uint_t)u) << 16;
    return __uint_as_float(v);
}
__device__ inline ushort_t f2b(float f){
    uint_t v = __float_as_uint(f);
    uint_t r = (v + 0x7FFFu + ((v >> 16) & 1u)) >> 16;  // RNE
    return (ushort_t)r;
}
__device__ inline void unpack8(uint4 u, float* f){
    uint_t w[4] = {u.x, u.y, u.z, u.w};
    #pragma unroll
    for (int i = 0; i < 4; ++i){
        f[2*i]   = __uint_as_float(w[i] << 16);
        f[2*i+1] = __uint_as_float(w[i] & 0xFFFF0000u);
    }
}
__device__ inline uint4 pack8(const float* f){
    uint4 o;
    uint_t w[4];
    #pragma unroll
    for (int i = 0; i < 4; ++i)
        w[i] = (uint_t)f2b(f[2*i]) | ((uint_t)f2b(f[2*i+1]) << 16);
    o.x = w[0]; o.y = w[1]; o.z = w[2]; o.w = w[3];
    return o;
}
__device__ inline ushort4 cvt4(float4 v){
    ushort4 o;
    o.x = f2b(v.x); o.y = f2b(v.y); o.z = f2b(v.z); o.w = f2b(v.w);
    return o;
}
__device__ inline float hswish(float y){
    return y * fminf(fmaxf(y + 3.f, 0.f), 6.f) * (1.f/6.f);
}

// ---------- constants ----------
#define MROWS 6272
#define CDIM  768
#define HID   3072
#define QKV3  2304

// swin window->spatial row map (with +3 roll): ri (window layout) -> dest row (b*196+p)
__device__ inline int scatter_row(int ri){
    int w  = ri / 49, t = ri % 49;
    int b  = w >> 2,  wi = w & 3;
    int wy = wi >> 1, wx = wi & 1;
    int ty = t / 7,   tx = t % 7;
    int yd = (wy*7 + ty + 3) % 14;
    int xd = (wx*7 + tx + 3) % 14;
    return b*196 + yd*14 + xd;
}

// ---------- fp32 -> bf16 cast (weights) ----------
__global__ __launch_bounds__(256) void cvt_f2b(const float4* __restrict__ in,
                                               ushort4* __restrict__ out, int n4){
    int i = blockIdx.x * 256 + threadIdx.x;
    if (i < n4) out[i] = cvt4(in[i]);
}

// ---------- dw weight transpose: [3072][9] -> [9][3072] ----------
__global__ __launch_bounds__(256) void dw_transpose(const float* __restrict__ w,
                                                    float* __restrict__ wT){
    int i = blockIdx.x*256 + threadIdx.x;
    if (i < HID*9){ int c = i/9, k = i%9; wT[k*HID + c] = w[i]; }
}

// ---------- window gather: x fp32 (B,197,C) -> win bf16 (128*49, C), shifted ----------
__global__ __launch_bounds__(256) void gather_win(const float4* __restrict__ x,
                                                  ushort4* __restrict__ win){
    int idx = blockIdx.x * 256 + threadIdx.x;
    if (idx >= MROWS * 192) return;
    int r  = idx / 192, c4 = idx % 192;
    int w  = r / 49,  t  = r % 49;
    int b  = w >> 2,  wi = w & 3;
    int wy = wi >> 1, wx = wi & 1;
    int ty = t / 7,   tx = t % 7;
    int ys = (wy*7 + ty + 3) % 14;                       // roll(-3)
    int xs = (wx*7 + tx + 3) % 14;
    win[idx] = cvt4(x[(size_t)b*197*192 + (size_t)(1 + ys*14 + xs)*192 + c4]);
}

// ---------- MFMA GEMM: C(MxN) = A(MxK) @ B(NxK)^T (+bias), bf16 in, fp32 acc ----------
// Launch with gridDim.y padded to a multiple of 8 (rows 128/ea).
// XCD swizzle: XCD (flat&7) owns rows == xcd (mod 8), sweeping columns consecutively
// so an A row-tile stays in that XCD's private 4MB L2 across all column blocks.
__global__ __launch_bounds__(256) void gemm_bt(const ushort_t* __restrict__ A,
                                               const ushort_t* __restrict__ B,
                                               ushort_t* __restrict__ Cb,
                                               float* __restrict__ Cf,
                                               int M, int N, int K,
                                               const float* __restrict__ bias,
                                               float* __restrict__ stats,
                                               int scat){
    const int nx   = gridDim.x;
    int flat = blockIdx.y * nx + blockIdx.x;
    int xcd  = flat & 7;
    int k    = flat >> 3;
    int by   = xcd + 8 * (k / nx);
    int bx   = k % nx;
    if (by * 128 >= M) return;

    __shared__ __align__(16) ushort_t As[128*32];
    __shared__ __align__(16) ushort_t Bs[128*32];
    const int tid  = threadIdx.x;
    const int lane = tid & 63;
    const int wid  = tid >> 6;
    const int m0 = by * 128;
    const int n0 = bx * 128;
    const int wm = (wid >> 1) * 64;
    const int wn = (wid & 1) * 64;

    floatx4 acc[4][4] = {};

    for (int k0 = 0; k0 < K; k0 += 32){
        __syncthreads();
        #pragma unroll
        for (int j = 0; j < 2; ++j){
            int ch  = wid*2 + j;
            int row = ch*16 + (lane >> 2);
            int col = (lane & 3) * 8;
            const ushort_t* gA = A + (size_t)(m0 + row)*K + k0 + col;
            const ushort_t* gB = B + (size_t)(n0 + row)*K + k0 + col;
            __builtin_amdgcn_global_load_lds(
                (const __attribute__((address_space(1))) void*)gA,
                (__attribute__((address_space(3))) void*)(As + ch*512 + lane*8), 16, 0, 0);
            __builtin_amdgcn_global_load_lds(
                (const __attribute__((address_space(1))) void*)gB,
                (__attribute__((address_space(3))) void*)(Bs + ch*512 + lane*8), 16, 0, 0);
        }
        __syncthreads();

        short8 af[4], bfr[4];
        const int fr = lane & 15;
        const int co = (lane >> 4) * 8;
        #pragma unroll
        for (int i = 0; i < 4; ++i){
            af[i]  = *(const short8*)(As + (wm + i*16 + fr)*32 + co);
            bfr[i] = *(const short8*)(Bs + (wn + i*16 + fr)*32 + co);
        }
        #pragma unroll
        for (int i = 0; i < 4; ++i)
            #pragma unroll
            for (int j = 0; j < 4; ++j)
                acc[i][j] = __builtin_amdgcn_mfma_f32_16x16x32_bf16(af[i], bfr[j], acc[i][j], 0, 0, 0);
    }

    // epilogue: C/D layout col=lane&15, row=(lane>>4)*4+r  [m89-verified]
    #pragma unroll
    for (int i = 0; i < 4; ++i){
        int grow = m0 + wm + i*16 + (lane >> 4)*4;
        #pragma unroll
        for (int j = 0; j < 4; ++j){
            int gcol = n0 + wn + j*16 + (lane & 15);
            float bv = bias ? bias[gcol] : 0.f;
            if (scat){
                #pragma unroll
                for (int r = 0; r < 4; ++r){
                    float v = acc[i][j][r] + bv;
                    size_t off = (size_t)scatter_row(grow + r)*N + gcol;
                    Cf[off] = v;
                    Cb[off] = f2b(v);
                }
            } else if (Cb){
                #pragma unroll
                for (int r = 0; r < 4; ++r)
                    Cb[(size_t)(grow + r)*N + gcol] = f2b(acc[i][j][r] + bv);
            } else {
                #pragma unroll
                for (int r = 0; r < 4; ++r)
                    Cf[(size_t)(grow + r)*N + gcol] = acc[i][j][r] + bv;
            }
        }
    }

    if (stats){
        // per-column (over M) sum / sumsq for batch-norm, fused.
        #pragma unroll
        for (int j = 0; j < 4; ++j){
            int gcol = n0 + wn + j*16 + (lane & 15);
            float bv = bias ? bias[gcol] : 0.f;
            float sv = 0.f, sq = 0.f;
            #pragma unroll
            for (int i = 0; i < 4; ++i)
                #pragma unroll
                for (int r = 0; r < 4; ++r){
                    float v = acc[i][j][r] + bv;
                    sv += v; sq += v*v;
                }
            sv += __shfl_xor(sv, 16, 64);  sq += __shfl_xor(sq, 16, 64);
            sv += __shfl_xor(sv, 32, 64);  sq += __shfl_xor(sq, 32, 64);
            if (lane < 16){
                atomicAdd(&stats[gcol], sv);
                atomicAdd(&stats[N + gcol], sq);
            }
        }
    }
}

// ---------- attention ----------
__global__ __launch_bounds__(256) void attn_kernel(const ushort_t* __restrict__ qkv,
                                                   ushort_t* __restrict__ outp,
                                                   const float* __restrict__ rpb){
    __shared__ float qs[49*65];
    __shared__ float ks[49*65];
    __shared__ float vs[49*65];
    __shared__ float Ss[49*50];
    __shared__ int   code[49];
    const int tid = threadIdx.x;
    const int h = blockIdx.x;
    const int w = blockIdx.y;
    const int wi = w & 3;
    const int wy = wi >> 1, wx = wi & 1;

    if (tid < 49){
        int ty = tid / 7, tx = tid % 7;
        int gy = wy*7 + ty, gx = wx*7 + tx;
        int ch = (gy < 7) ? 0 : (gy < 11 ? 1 : 2);
        int cw = (gx < 7) ? 0 : (gx < 11 ? 1 : 2);
        code[tid] = ch*3 + cw;
    }
    for (int idx = tid; idx < 49*64; idx += 256){
        int t = idx >> 6, d = idx & 63;
        size_t base = (size_t)(w*49 + t)*QKV3 + h*64 + d;
        qs[t*65 + d] = b2f(qkv[base]) * 0.125f;
        ks[t*65 + d] = b2f(qkv[base + 768]);
        vs[t*65 + d] = b2f(qkv[base + 1536]);
    }
    __syncthreads();

    for (int idx = tid; idx < 49*49; idx += 256){
        int qi = idx / 49, ki = idx - qi*49;
        const float* qr = qs + qi*65;
        const float* kr = ks + ki*65;
        float a = 0.f;
        #pragma unroll 8
        for (int d = 0; d < 64; ++d) a += qr[d]*kr[d];
        int qy = qi/7, qx = qi%7, ky = ki/7, kx = ki%7;
        int ridx = (qy - ky + 6)*13 + (qx - kx + 6);
        a += rpb[ridx*12 + h];
        if (code[qi] != code[ki]) a -= 100.f;
        Ss[qi*50 + ki] = a;
    }
    __syncthreads();

    if (tid < 49){
        float* row = Ss + tid*50;
        float m = row[0];
        for (int k = 1; k < 49; ++k) m = fmaxf(m, row[k]);
        float s = 0.f;
        for (int k = 0; k < 49; ++k){ float e = __expf(row[k] - m); row[k] = e; s += e; }
        float inv = 1.f / s;
        for (int k = 0; k < 49; ++k) row[k] *= inv;
    }
    __syncthreads();

    for (int idx = tid; idx < 49*64; idx += 256){
        int qi = idx >> 6, d = idx & 63;
        const float* sr = Ss + qi*50;
        const float* vc = vs + d;
        float a = 0.f;
        #pragma unroll 7
        for (int k = 0; k < 49; ++k) a += sr[k]*vc[k*65];
        outp[(size_t)(w*49 + qi)*CDIM + h*64 + d] = f2b(a);
    }
}

// ---------- BN ----------
__global__ void zero_f32(float* __restrict__ p, int n){
    int i = blockIdx.x*256 + threadIdx.x;
    if (i < n) p[i] = 0.f;
}
__global__ __launch_bounds__(256) void bn_stats(const ushort_t* __restrict__ X,
                                                float* __restrict__ sums, int Cch){
    int c  = blockIdx.x*256 + threadIdx.x;
    int r0 = blockIdx.y * 784;
    float s = 0.f, s2 = 0.f;
    for (int r = r0; r < r0 + 784; ++r){
        float v = b2f(X[(size_t)r*Cch + c]);
        s += v; s2 += v*v;
    }
    atomicAdd(&sums[c], s);
    atomicAdd(&sums[Cch + c], s2);
}
__global__ void bn_finalize(float* __restrict__ sums, const float* __restrict__ g,
                            const float* __restrict__ b, int Cch){
    int c = blockIdx.x*256 + threadIdx.x;
    if (c >= Cch) return;
    float mean = sums[c] * (1.f/6272.f);
    float var  = sums[Cch + c] * (1.f/6272.f) - mean*mean;
    float sc = g[c] * rsqrtf(var + 1e-5f);
    sums[c] = sc;
    sums[Cch + c] = b[c] - mean*sc;
}

// ---------- depthwise 3x3, vectorized, bn1+hswish fused on input ----------
__global__ __launch_bounds__(256) void dwconv_v(const ushort_t* __restrict__ in,
                                                const float* __restrict__ wT,
                                                const float* __restrict__ ss,
                                                ushort_t* __restrict__ out){
    int idx = blockIdx.x*256 + threadIdx.x;      // over MROWS*384
    if (idx >= MROWS*384) return;
    int r  = idx / 384, cg = idx % 384;
    int b  = r / 196,  p  = r % 196;
    int y  = p / 14,   x  = p % 14;
    int c  = cg*8;
    const uint4* inb = (const uint4*)(in + (size_t)b*196*HID);
    float sc[8], sh[8];
    {
        const float4* s0 = (const float4*)(ss + c);
        const float4* s1 = (const float4*)(ss + HID + c);
        float4 a0 = s0[0], a1 = s0[1], b0 = s1[0], b1 = s1[1];
        sc[0]=a0.x; sc[1]=a0.y; sc[2]=a0.z; sc[3]=a0.w;
        sc[4]=a1.x; sc[5]=a1.y; sc[6]=a1.z; sc[7]=a1.w;
        sh[0]=b0.x; sh[1]=b0.y; sh[2]=b0.z; sh[3]=b0.w;
        sh[4]=b1.x; sh[5]=b1.y; sh[6]=b1.z; sh[7]=b1.w;
    }
    float acc[8] = {};
    #pragma unroll
    for (int ky = 0; ky < 3; ++ky){
        int yy = y + ky - 1;
        if ((unsigned)yy >= 14u) continue;
        #pragma unroll
        for (int kx = 0; kx < 3; ++kx){
            int xx = x + kx - 1;
            if ((unsigned)xx >= 14u) continue;
            uint4 u = inb[(yy*14 + xx)*384 + cg];
            float fin[8]; unpack8(u, fin);
            const float4* wp = (const float4*)(wT + (ky*3 + kx)*HID + c);
            float4 w0 = wp[0], w1 = wp[1];
            float wv[8] = {w0.x,w0.y,w0.z,w0.w,w1.x,w1.y,w1.z,w1.w};
            #pragma unroll
            for (int e = 0; e < 8; ++e)
                acc[e] += hswish(fin[e]*sc[e] + sh[e]) * wv[e];
        }
    }
    ((uint4*)out)[idx] = pack8(acc);
}

// ---------- SE (bn2+hswish fused on read) ----------
__global__ __launch_bounds__(256) void se_mean(const ushort_t* __restrict__ X,
                                               const float* __restrict__ ss,
                                               float* __restrict__ s){
    int b = blockIdx.x;
    int c = blockIdx.y*256 + threadIdx.x;
    float sc = ss[c], sh = ss[HID + c];
    float a = 0.f;
    for (int p = 0; p < 196; ++p)
        a += hswish(b2f(X[((size_t)b*196 + p)*HID + c])*sc + sh);
    s[b*HID + c] = a * (1.f/196.f);
}
__global__ __launch_bounds__(256) void se_fc(const float* __restrict__ in,
                                             const float* __restrict__ w,
                                             const float* __restrict__ bias,
                                             float* __restrict__ out,
                                             int IN, int OUT, int mode){
    int wv   = (blockIdx.x*256 + threadIdx.x) >> 6;
    int lane = threadIdx.x & 63;
    if (wv >= OUT) return;
    const float* wr = w + (size_t)wv * IN;
    float acc[32];
    #pragma unroll
    for (int b = 0; b < 32; ++b) acc[b] = 0.f;
    for (int k = lane; k < IN; k += 64){
        float wval = wr[k];
        #pragma unroll
        for (int b = 0; b < 32; ++b)
            acc[b] += in[b*IN + k] * wval;
    }
    #pragma unroll
    for (int b = 0; b < 32; ++b){
        float v = acc[b];
        #pragma unroll
        for (int off = 32; off; off >>= 1) v += __shfl_down(v, off, 64);
        if (lane == 0){
            float a = v + bias[wv];
            if (mode == 0) a = fmaxf(a, 0.f);
            else           a = fminf(fmaxf(a + 3.f, 0.f), 6.f) * (1.f/6.f);
            out[b*OUT + wv] = a;
        }
    }
}
// bn2+hswish+SE-scale in one pass: writes pw2's bf16 input in place
__global__ __launch_bounds__(256) void se_scale(ushort_t* __restrict__ X,
                                                const float* __restrict__ ss,
                                                const float* __restrict__ s2){
    int idx = blockIdx.x*256 + threadIdx.x;
    if (idx >= MROWS * (HID/8)) return;
    int r = idx / (HID/8), c8 = idx % (HID/8);
    int b = r / 196;
    int c = c8*8;
    uint4 u = ((uint4*)X)[idx];
    float f[8]; unpack8(u, f);
    const float* sp = s2 + b*HID + c;
    #pragma unroll
    for (int e = 0; e < 8; ++e)
        f[e] = hswish(f[e]*ss[c+e] + ss[HID+c+e]) * sp[e];
    ((uint4*)X)[idx] = pack8(f);
}

// ---------- final ----------
__global__ __launch_bounds__(256) void final_k(const float4* __restrict__ xin,
                                               const float4* __restrict__ f,
                                               const float4* __restrict__ h4,
                                               const float* __restrict__ ss,
                                               float4* __restrict__ outp){
    int idx = blockIdx.x*256 + threadIdx.x;
    if (idx >= 32*197*192) return;
    int b = idx / (197*192);
    int rem = idx % (197*192);
    int n = rem / 192, c4 = rem % 192;
    if (n == 0){ outp[idx] = xin[idx]; return; }
    size_t off = ((size_t)b*196 + n - 1)*192 + c4;
    float4 hv = h4[off];
    float4 fv = f[off];
    float4 o;
    int c = c4*4;
    o.x = fv.x + hv.x*ss[c+0] + ss[CDIM + c+0];
    o.y = fv.y + hv.y*ss[c+1] + ss[CDIM + c+1];
    o.z = fv.z + hv.z*ss[c+2] + ss[CDIM + c+2];
    o.w = fv.w + hv.w*ss[c+3] + ss[CDIM + c+3];
    outp[idx] = o;
}

extern "C" void kernel_launch(void* const* d_in, const int* in_sizes, int n_in,
                              void* d_out, int out_size, void* d_ws, size_t ws_size,
                              hipStream_t stream){
    const float* x      = (const float*)d_in[0];
    const float* w_qkv  = (const float*)d_in[1];
    const float* w_proj = (const float*)d_in[2];
    const float* b_proj = (const float*)d_in[3];
    const float* rpb    = (const float*)d_in[4];
    const float* pw1_w  = (const float*)d_in[5];
    const float* bn1_g  = (const float*)d_in[6];
    const float* bn1_b  = (const float*)d_in[7];
    const float* dw_w   = (const float*)d_in[8];
    const float* bn2_g  = (const float*)d_in[9];
    const float* bn2_b  = (const float*)d_in[10];
    const float* se_w1  = (const float*)d_in[11];
    const float* se_b1  = (const float*)d_in[12];
    const float* se_w2  = (const float*)d_in[13];
    const float* se_b2  = (const float*)d_in[14];
    const float* pw2_w  = (const float*)d_in[15];
    const float* bn3_g  = (const float*)d_in[16];
    const float* bn3_b  = (const float*)d_in[17];

    char* ws = (char*)d_ws;
    ushort_t* win    = (ushort_t*)(ws + 0);
    ushort_t* qkv    = (ushort_t*)(ws + 9633792);
    ushort_t* fbf    = (ushort_t*)(ws + 0);
    ushort_t* pw1b   = (ushort_t*)(ws + 9633792);
    ushort_t* hb     = (ushort_t*)(ws + 0);
    ushort_t* wqkvb  = (ushort_t*)(ws + 38535168);
    ushort_t* attnb  = (ushort_t*)(ws + 38535168);
    ushort_t* wprojb = (ushort_t*)(ws + 48168960);
    ushort_t* ha     = (ushort_t*)(ws + 38535168);
    float*    h4     = (float*)(ws + 38535168);
    ushort_t* pw2b   = (ushort_t*)(ws + 57802752);
    float*    f      = (float*)(ws + 77070336);
    float*    stats  = (float*)(ws + 96337920);
    float*    s      = (float*)(ws + 96362496);
    float*    s1     = (float*)(ws + 96755712);
    float*    s2     = (float*)(ws + 96854016);
    float*    dwwT   = (float*)(ws + 96854016);   // alias s2: dead before se_fc writes s2

    const int vec_rows = (MROWS*192 + 255)/256;
    const int vec_hid8 = (MROWS*(HID/8) + 255)/256;
    const int GY = 56;   // 49 row-blocks padded to multiple of 8 for XCD swizzle

    // early weight prep (regions free at this point)
    dw_transpose<<<(HID*9 + 255)/256, 256, 0, stream>>>(dw_w, dwwT);
    cvt_f2b<<<(QKV3*CDIM/4 + 255)/256, 256, 0, stream>>>((const float4*)w_qkv, (ushort4*)wqkvb, QKV3*CDIM/4);
    cvt_f2b<<<(CDIM*CDIM/4 + 255)/256, 256, 0, stream>>>((const float4*)w_proj, (ushort4*)wprojb, CDIM*CDIM/4);

    // attention half
    gather_win<<<vec_rows, 256, 0, stream>>>((const float4*)x, (ushort4*)win);
    gemm_bt<<<dim3(QKV3/128, GY), 256, 0, stream>>>(win, wqkvb, qkv, nullptr, MROWS, QKV3, CDIM, nullptr, nullptr, 0);
    attn_kernel<<<dim3(12, 128), 256, 0, stream>>>(qkv, attnb, rpb);
    cvt_f2b<<<(HID*CDIM/4 + 255)/256, 256, 0, stream>>>((const float4*)pw1_w, (ushort4*)pw1b, HID*CDIM/4);  // qkv dead
    zero_f32<<<24, 256, 0, stream>>>(stats, 2*HID);   // for fused bn1 stats
    gemm_bt<<<dim3(CDIM/128, GY), 256, 0, stream>>>(attnb, wprojb, fbf, f, MROWS, CDIM, CDIM, b_proj, nullptr, 1);

    // ConvFFN half
    gemm_bt<<<dim3(HID/128, GY), 256, 0, stream>>>(fbf, pw1b, ha, nullptr, MROWS, HID, CDIM, nullptr, stats, 0);
    bn_finalize<<<HID/256, 256, 0, stream>>>(stats, bn1_g, bn1_b, HID);

    dwconv_v<<<(MROWS*384 + 255)/256, 256, 0, stream>>>(ha, dwwT, stats, hb);   // bn1+hswish fused
    cvt_f2b<<<(CDIM*HID/4 + 255)/256, 256, 0, stream>>>((const float4*)pw2_w, (ushort4*)pw2b, CDIM*HID/4);  // ha dead
    zero_f32<<<24, 256, 0, stream>>>(stats, 2*HID);
    bn_stats<<<dim3(HID/256, 8), 256, 0, stream>>>(hb, stats, HID);
    bn_finalize<<<HID/256, 256, 0, stream>>>(stats, bn2_g, bn2_b, HID);

    se_mean<<<dim3(32, HID/256), 256, 0, stream>>>(hb, stats, s);               // bn2+hswish fused
    se_fc<<<dim3((CDIM*64)/256), 256, 0, stream>>>(s, se_w1, se_b1, s1, HID, CDIM, 0);
    se_fc<<<dim3((HID*64)/256), 256, 0, stream>>>(s1, se_w2, se_b2, s2, CDIM, HID, 1);
    se_scale<<<vec_hid8, 256, 0, stream>>>(hb, stats, s2);                      // bn2+hswish+SE in one pass

    zero_f32<<<6, 256, 0, stream>>>(stats, 2*CDIM);   // for fused bn3 stats
    gemm_bt<<<dim3(CDIM/128, GY), 256, 0, stream>>>(hb, pw2b, nullptr, h4, MROWS, CDIM, HID, nullptr, stats, 0);
    bn_finalize<<<CDIM/256, 256, 0, stream>>>(stats, bn3_g, bn3_b, CDIM);
    final_k<<<(32*197*192 + 255)/256, 256, 0, stream>>>((const float4*)x, (const float4*)f, (const float4*)h4, stats, (float4*)d_out);
}

// Round 7
// 671.683 us; speedup vs baseline: 1.9374x; 1.0210x over previous
//
#include <hip/hip_runtime.h>
#include <hip/hip_bf16.h>

typedef unsigned short ushort_t;
typedef unsigned int uint_t;
typedef short short8 __attribute__((ext_vector_type(8)));
typedef float floatx4 __attribute__((ext_vector_type(4)));

// ---------- bf16 helpers (raw ushort storage) ----------
__device__ inline float b2f(ushort_t u){
    uint_t v = ((uint_t)u) << 16;
    return __uint_as_float(v);
}
__device__ inline ushort_t f2b(float f){
    uint_t v = __float_as_uint(f);
    uint_t r = (v + 0x7FFFu + ((v >> 16) & 1u)) >> 16;  // RNE
    return (ushort_t)r;
}
__device__ inline void unpack8(uint4 u, float* f){
    uint_t w[4] = {u.x, u.y, u.z, u.w};
    #pragma unroll
    for (int i = 0; i < 4; ++i){
        f[2*i]   = __uint_as_float(w[i] << 16);
        f[2*i+1] = __uint_as_float(w[i] & 0xFFFF0000u);
    }
}
__device__ inline uint4 pack8(const float* f){
    uint4 o;
    uint_t w[4];
    #pragma unroll
    for (int i = 0; i < 4; ++i)
        w[i] = (uint_t)f2b(f[2*i]) | ((uint_t)f2b(f[2*i+1]) << 16);
    o.x = w[0]; o.y = w[1]; o.z = w[2]; o.w = w[3];
    return o;
}
__device__ inline ushort4 cvt4(float4 v){
    ushort4 o;
    o.x = f2b(v.x); o.y = f2b(v.y); o.z = f2b(v.z); o.w = f2b(v.w);
    return o;
}
__device__ inline float hswish(float y){
    return y * fminf(fmaxf(y + 3.f, 0.f), 6.f) * (1.f/6.f);
}

// ---------- constants ----------
#define MROWS 6272
#define CDIM  768
#define HID   3072
#define QKV3  2304

// swin window->spatial row map (with +3 roll): ri (window layout) -> dest row (b*196+p)
__device__ inline int scatter_row(int ri){
    int w  = ri / 49, t = ri % 49;
    int b  = w >> 2,  wi = w & 3;
    int wy = wi >> 1, wx = wi & 1;
    int ty = t / 7,   tx = t % 7;
    int yd = (wy*7 + ty + 3) % 14;
    int xd = (wx*7 + tx + 3) % 14;
    return b*196 + yd*14 + xd;
}

// ---------- fp32 -> bf16 cast (weights) ----------
__global__ __launch_bounds__(256) void cvt_f2b(const float4* __restrict__ in,
                                               ushort4* __restrict__ out, int n4){
    int i = blockIdx.x * 256 + threadIdx.x;
    if (i < n4) out[i] = cvt4(in[i]);
}

// ---------- dw weight transpose: [3072][9] -> [9][3072] ----------
__global__ __launch_bounds__(256) void dw_transpose(const float* __restrict__ w,
                                                    float* __restrict__ wT){
    int i = blockIdx.x*256 + threadIdx.x;
    if (i < HID*9){ int c = i/9, k = i%9; wT[k*HID + c] = w[i]; }
}

// ---------- window gather: x fp32 (B,197,C) -> win bf16 (128*49, C), shifted ----------
__global__ __launch_bounds__(256) void gather_win(const float4* __restrict__ x,
                                                  ushort4* __restrict__ win){
    int idx = blockIdx.x * 256 + threadIdx.x;
    if (idx >= MROWS * 192) return;
    int r  = idx / 192, c4 = idx % 192;
    int w  = r / 49,  t  = r % 49;
    int b  = w >> 2,  wi = w & 3;
    int wy = wi >> 1, wx = wi & 1;
    int ty = t / 7,   tx = t % 7;
    int ys = (wy*7 + ty + 3) % 14;                       // roll(-3)
    int xs = (wx*7 + tx + 3) % 14;
    win[idx] = cvt4(x[(size_t)b*197*192 + (size_t)(1 + ys*14 + xs)*192 + c4]);
}

// ---------- MFMA GEMM 128x128 tile (qkv / pw1) ----------
__global__ __launch_bounds__(256) void gemm_bt(const ushort_t* __restrict__ A,
                                               const ushort_t* __restrict__ B,
                                               ushort_t* __restrict__ Cb,
                                               float* __restrict__ Cf,
                                               int M, int N, int K,
                                               const float* __restrict__ bias,
                                               float* __restrict__ stats,
                                               int scat){
    const int nx   = gridDim.x;
    int flat = blockIdx.y * nx + blockIdx.x;
    int xcd  = flat & 7;
    int k    = flat >> 3;
    int by   = xcd + 8 * (k / nx);
    int bx   = k % nx;
    if (by * 128 >= M) return;

    __shared__ __align__(16) ushort_t As[128*32];
    __shared__ __align__(16) ushort_t Bs[128*32];
    const int tid  = threadIdx.x;
    const int lane = tid & 63;
    const int wid  = tid >> 6;
    const int m0 = by * 128;
    const int n0 = bx * 128;
    const int wm = (wid >> 1) * 64;
    const int wn = (wid & 1) * 64;

    floatx4 acc[4][4] = {};

    for (int k0 = 0; k0 < K; k0 += 32){
        __syncthreads();
        #pragma unroll
        for (int j = 0; j < 2; ++j){
            int ch  = wid*2 + j;
            int row = ch*16 + (lane >> 2);
            int col = (lane & 3) * 8;
            const ushort_t* gA = A + (size_t)(m0 + row)*K + k0 + col;
            const ushort_t* gB = B + (size_t)(n0 + row)*K + k0 + col;
            __builtin_amdgcn_global_load_lds(
                (const __attribute__((address_space(1))) void*)gA,
                (__attribute__((address_space(3))) void*)(As + ch*512 + lane*8), 16, 0, 0);
            __builtin_amdgcn_global_load_lds(
                (const __attribute__((address_space(1))) void*)gB,
                (__attribute__((address_space(3))) void*)(Bs + ch*512 + lane*8), 16, 0, 0);
        }
        __syncthreads();

        short8 af[4], bfr[4];
        const int fr = lane & 15;
        const int co = (lane >> 4) * 8;
        #pragma unroll
        for (int i = 0; i < 4; ++i){
            af[i]  = *(const short8*)(As + (wm + i*16 + fr)*32 + co);
            bfr[i] = *(const short8*)(Bs + (wn + i*16 + fr)*32 + co);
        }
        #pragma unroll
        for (int i = 0; i < 4; ++i)
            #pragma unroll
            for (int j = 0; j < 4; ++j)
                acc[i][j] = __builtin_amdgcn_mfma_f32_16x16x32_bf16(af[i], bfr[j], acc[i][j], 0, 0, 0);
    }

    #pragma unroll
    for (int i = 0; i < 4; ++i){
        int grow = m0 + wm + i*16 + (lane >> 4)*4;
        #pragma unroll
        for (int j = 0; j < 4; ++j){
            int gcol = n0 + wn + j*16 + (lane & 15);
            float bv = bias ? bias[gcol] : 0.f;
            if (scat){
                #pragma unroll
                for (int r = 0; r < 4; ++r){
                    float v = acc[i][j][r] + bv;
                    size_t off = (size_t)scatter_row(grow + r)*N + gcol;
                    Cf[off] = v;
                    Cb[off] = f2b(v);
                }
            } else if (Cb){
                #pragma unroll
                for (int r = 0; r < 4; ++r)
                    Cb[(size_t)(grow + r)*N + gcol] = f2b(acc[i][j][r] + bv);
            } else {
                #pragma unroll
                for (int r = 0; r < 4; ++r)
                    Cf[(size_t)(grow + r)*N + gcol] = acc[i][j][r] + bv;
            }
        }
    }

    if (stats){
        #pragma unroll
        for (int j = 0; j < 4; ++j){
            int gcol = n0 + wn + j*16 + (lane & 15);
            float bv = bias ? bias[gcol] : 0.f;
            float sv = 0.f, sq = 0.f;
            #pragma unroll
            for (int i = 0; i < 4; ++i)
                #pragma unroll
                for (int r = 0; r < 4; ++r){
                    float v = acc[i][j][r] + bv;
                    sv += v; sq += v*v;
                }
            sv += __shfl_xor(sv, 16, 64);  sq += __shfl_xor(sq, 16, 64);
            sv += __shfl_xor(sv, 32, 64);  sq += __shfl_xor(sq, 32, 64);
            if (lane < 16){
                atomicAdd(&stats[gcol], sv);
                atomicAdd(&stats[N + gcol], sq);
            }
        }
    }
}

// ---------- MFMA GEMM 128x64 tile (proj / pw2: small N -> more blocks/CU) ----------
// 4 waves of 64x32; 3 staging loads + 8 MFMA per K-iter; acc[4][2].
__global__ __launch_bounds__(256) void gemm_bt64(const ushort_t* __restrict__ A,
                                                 const ushort_t* __restrict__ B,
                                                 ushort_t* __restrict__ Cb,
                                                 float* __restrict__ Cf,
                                                 int M, int N, int K,
                                                 const float* __restrict__ bias,
                                                 float* __restrict__ stats,
                                                 int scat){
    const int nx   = gridDim.x;
    int flat = blockIdx.y * nx + blockIdx.x;
    int xcd  = flat & 7;
    int k    = flat >> 3;
    int by   = xcd + 8 * (k / nx);
    int bx   = k % nx;
    if (by * 128 >= M) return;

    __shared__ __align__(16) ushort_t As[128*32];
    __shared__ __align__(16) ushort_t Bs[64*32];
    const int tid  = threadIdx.x;
    const int lane = tid & 63;
    const int wid  = tid >> 6;
    const int m0 = by * 128;
    const int n0 = bx * 64;
    const int wm = (wid >> 1) * 64;
    const int wn = (wid & 1) * 32;

    floatx4 acc[4][2] = {};

    for (int k0 = 0; k0 < K; k0 += 32){
        __syncthreads();
        {
            int row = (lane >> 2);
            int col = (lane & 3) * 8;
            #pragma unroll
            for (int j = 0; j < 2; ++j){
                int ch = wid*2 + j;
                const ushort_t* gA = A + (size_t)(m0 + ch*16 + row)*K + k0 + col;
                __builtin_amdgcn_global_load_lds(
                    (const __attribute__((address_space(1))) void*)gA,
                    (__attribute__((address_space(3))) void*)(As + ch*512 + lane*8), 16, 0, 0);
            }
            const ushort_t* gB = B + (size_t)(n0 + wid*16 + row)*K + k0 + col;
            __builtin_amdgcn_global_load_lds(
                (const __attribute__((address_space(1))) void*)gB,
                (__attribute__((address_space(3))) void*)(Bs + wid*512 + lane*8), 16, 0, 0);
        }
        __syncthreads();

        short8 af[4], bfr[2];
        const int fr = lane & 15;
        const int co = (lane >> 4) * 8;
        #pragma unroll
        for (int i = 0; i < 4; ++i)
            af[i]  = *(const short8*)(As + (wm + i*16 + fr)*32 + co);
        #pragma unroll
        for (int j = 0; j < 2; ++j)
            bfr[j] = *(const short8*)(Bs + (wn + j*16 + fr)*32 + co);
        #pragma unroll
        for (int i = 0; i < 4; ++i)
            #pragma unroll
            for (int j = 0; j < 2; ++j)
                acc[i][j] = __builtin_amdgcn_mfma_f32_16x16x32_bf16(af[i], bfr[j], acc[i][j], 0, 0, 0);
    }

    #pragma unroll
    for (int i = 0; i < 4; ++i){
        int grow = m0 + wm + i*16 + (lane >> 4)*4;
        #pragma unroll
        for (int j = 0; j < 2; ++j){
            int gcol = n0 + wn + j*16 + (lane & 15);
            float bv = bias ? bias[gcol] : 0.f;
            if (scat){
                #pragma unroll
                for (int r = 0; r < 4; ++r){
                    float v = acc[i][j][r] + bv;
                    size_t off = (size_t)scatter_row(grow + r)*N + gcol;
                    Cf[off] = v;
                    Cb[off] = f2b(v);
                }
            } else if (Cb){
                #pragma unroll
                for (int r = 0; r < 4; ++r)
                    Cb[(size_t)(grow + r)*N + gcol] = f2b(acc[i][j][r] + bv);
            } else {
                #pragma unroll
                for (int r = 0; r < 4; ++r)
                    Cf[(size_t)(grow + r)*N + gcol] = acc[i][j][r] + bv;
            }
        }
    }

    if (stats){
        #pragma unroll
        for (int j = 0; j < 2; ++j){
            int gcol = n0 + wn + j*16 + (lane & 15);
            float bv = bias ? bias[gcol] : 0.f;
            float sv = 0.f, sq = 0.f;
            #pragma unroll
            for (int i = 0; i < 4; ++i)
                #pragma unroll
                for (int r = 0; r < 4; ++r){
                    float v = acc[i][j][r] + bv;
                    sv += v; sq += v*v;
                }
            sv += __shfl_xor(sv, 16, 64);  sq += __shfl_xor(sq, 16, 64);
            sv += __shfl_xor(sv, 32, 64);  sq += __shfl_xor(sq, 32, 64);
            if (lane < 16){
                atomicAdd(&stats[gcol], sv);
                atomicAdd(&stats[N + gcol], sq);
            }
        }
    }
}

// ---------- attention ----------
__global__ __launch_bounds__(256) void attn_kernel(const ushort_t* __restrict__ qkv,
                                                   ushort_t* __restrict__ outp,
                                                   const float* __restrict__ rpb){
    __shared__ float qs[49*65];
    __shared__ float ks[49*65];
    __shared__ float vs[49*65];
    __shared__ float Ss[49*50];
    __shared__ int   code[49];
    const int tid = threadIdx.x;
    const int h = blockIdx.x;
    const int w = blockIdx.y;
    const int wi = w & 3;
    const int wy = wi >> 1, wx = wi & 1;

    if (tid < 49){
        int ty = tid / 7, tx = tid % 7;
        int gy = wy*7 + ty, gx = wx*7 + tx;
        int ch = (gy < 7) ? 0 : (gy < 11 ? 1 : 2);
        int cw = (gx < 7) ? 0 : (gx < 11 ? 1 : 2);
        code[tid] = ch*3 + cw;
    }
    for (int idx = tid; idx < 49*64; idx += 256){
        int t = idx >> 6, d = idx & 63;
        size_t base = (size_t)(w*49 + t)*QKV3 + h*64 + d;
        qs[t*65 + d] = b2f(qkv[base]) * 0.125f;
        ks[t*65 + d] = b2f(qkv[base + 768]);
        vs[t*65 + d] = b2f(qkv[base + 1536]);
    }
    __syncthreads();

    for (int idx = tid; idx < 49*49; idx += 256){
        int qi = idx / 49, ki = idx - qi*49;
        const float* qr = qs + qi*65;
        const float* kr = ks + ki*65;
        float a = 0.f;
        #pragma unroll 8
        for (int d = 0; d < 64; ++d) a += qr[d]*kr[d];
        int qy = qi/7, qx = qi%7, ky = ki/7, kx = ki%7;
        int ridx = (qy - ky + 6)*13 + (qx - kx + 6);
        a += rpb[ridx*12 + h];
        if (code[qi] != code[ki]) a -= 100.f;
        Ss[qi*50 + ki] = a;
    }
    __syncthreads();

    if (tid < 49){
        float* row = Ss + tid*50;
        float m = row[0];
        for (int k = 1; k < 49; ++k) m = fmaxf(m, row[k]);
        float s = 0.f;
        for (int k = 0; k < 49; ++k){ float e = __expf(row[k] - m); row[k] = e; s += e; }
        float inv = 1.f / s;
        for (int k = 0; k < 49; ++k) row[k] *= inv;
    }
    __syncthreads();

    for (int idx = tid; idx < 49*64; idx += 256){
        int qi = idx >> 6, d = idx & 63;
        const float* sr = Ss + qi*50;
        const float* vc = vs + d;
        float a = 0.f;
        #pragma unroll 7
        for (int k = 0; k < 49; ++k) a += sr[k]*vc[k*65];
        outp[(size_t)(w*49 + qi)*CDIM + h*64 + d] = f2b(a);
    }
}

// ---------- BN ----------
__global__ void zero_f32(float* __restrict__ p, int n){
    int i = blockIdx.x*256 + threadIdx.x;
    if (i < n) p[i] = 0.f;
}
__global__ __launch_bounds__(256) void bn_stats(const ushort_t* __restrict__ X,
                                                float* __restrict__ sums, int Cch){
    int c  = blockIdx.x*256 + threadIdx.x;
    int r0 = blockIdx.y * 784;
    float s = 0.f, s2 = 0.f;
    for (int r = r0; r < r0 + 784; ++r){
        float v = b2f(X[(size_t)r*Cch + c]);
        s += v; s2 += v*v;
    }
    atomicAdd(&sums[c], s);
    atomicAdd(&sums[Cch + c], s2);
}
__global__ void bn_finalize(float* __restrict__ sums, const float* __restrict__ g,
                            const float* __restrict__ b, int Cch){
    int c = blockIdx.x*256 + threadIdx.x;
    if (c >= Cch) return;
    float mean = sums[c] * (1.f/6272.f);
    float var  = sums[Cch + c] * (1.f/6272.f) - mean*mean;
    float sc = g[c] * rsqrtf(var + 1e-5f);
    sums[c] = sc;
    sums[Cch + c] = b[c] - mean*sc;
}

// ---------- depthwise 3x3, vectorized, bn1+hswish fused on input ----------
__global__ __launch_bounds__(256) void dwconv_v(const ushort_t* __restrict__ in,
                                                const float* __restrict__ wT,
                                                const float* __restrict__ ss,
                                                ushort_t* __restrict__ out){
    int idx = blockIdx.x*256 + threadIdx.x;      // over MROWS*384
    if (idx >= MROWS*384) return;
    int r  = idx / 384, cg = idx % 384;
    int b  = r / 196,  p  = r % 196;
    int y  = p / 14,   x  = p % 14;
    int c  = cg*8;
    const uint4* inb = (const uint4*)(in + (size_t)b*196*HID);
    float sc[8], sh[8];
    {
        const float4* s0 = (const float4*)(ss + c);
        const float4* s1 = (const float4*)(ss + HID + c);
        float4 a0 = s0[0], a1 = s0[1], b0 = s1[0], b1 = s1[1];
        sc[0]=a0.x; sc[1]=a0.y; sc[2]=a0.z; sc[3]=a0.w;
        sc[4]=a1.x; sc[5]=a1.y; sc[6]=a1.z; sc[7]=a1.w;
        sh[0]=b0.x; sh[1]=b0.y; sh[2]=b0.z; sh[3]=b0.w;
        sh[4]=b1.x; sh[5]=b1.y; sh[6]=b1.z; sh[7]=b1.w;
    }
    float acc[8] = {};
    #pragma unroll
    for (int ky = 0; ky < 3; ++ky){
        int yy = y + ky - 1;
        if ((unsigned)yy >= 14u) continue;
        #pragma unroll
        for (int kx = 0; kx < 3; ++kx){
            int xx = x + kx - 1;
            if ((unsigned)xx >= 14u) continue;
            uint4 u = inb[(yy*14 + xx)*384 + cg];
            float fin[8]; unpack8(u, fin);
            const float4* wp = (const float4*)(wT + (ky*3 + kx)*HID + c);
            float4 w0 = wp[0], w1 = wp[1];
            float wv[8] = {w0.x,w0.y,w0.z,w0.w,w1.x,w1.y,w1.z,w1.w};
            #pragma unroll
            for (int e = 0; e < 8; ++e)
                acc[e] += hswish(fin[e]*sc[e] + sh[e]) * wv[e];
        }
    }
    ((uint4*)out)[idx] = pack8(acc);
}

// ---------- SE (bn2+hswish fused on read) ----------
__global__ __launch_bounds__(256) void se_mean(const ushort_t* __restrict__ X,
                                               const float* __restrict__ ss,
                                               float* __restrict__ s){
    int b = blockIdx.x;
    int c = blockIdx.y*256 + threadIdx.x;
    float sc = ss[c], sh = ss[HID + c];
    float a = 0.f;
    for (int p = 0; p < 196; ++p)
        a += hswish(b2f(X[((size_t)b*196 + p)*HID + c])*sc + sh);
    s[b*HID + c] = a * (1.f/196.f);
}
__global__ __launch_bounds__(256) void se_fc(const float* __restrict__ in,
                                             const float* __restrict__ w,
                                             const float* __restrict__ bias,
                                             float* __restrict__ out,
                                             int IN, int OUT, int mode){
    int wv   = (blockIdx.x*256 + threadIdx.x) >> 6;
    int lane = threadIdx.x & 63;
    if (wv >= OUT) return;
    const float* wr = w + (size_t)wv * IN;
    float acc[32];
    #pragma unroll
    for (int b = 0; b < 32; ++b) acc[b] = 0.f;
    for (int k = lane; k < IN; k += 64){
        float wval = wr[k];
        #pragma unroll
        for (int b = 0; b < 32; ++b)
            acc[b] += in[b*IN + k] * wval;
    }
    #pragma unroll
    for (int b = 0; b < 32; ++b){
        float v = acc[b];
        #pragma unroll
        for (int off = 32; off; off >>= 1) v += __shfl_down(v, off, 64);
        if (lane == 0){
            float a = v + bias[wv];
            if (mode == 0) a = fmaxf(a, 0.f);
            else           a = fminf(fmaxf(a + 3.f, 0.f), 6.f) * (1.f/6.f);
            out[b*OUT + wv] = a;
        }
    }
}
// bn2+hswish+SE-scale in one pass: writes pw2's bf16 input in place
__global__ __launch_bounds__(256) void se_scale(ushort_t* __restrict__ X,
                                                const float* __restrict__ ss,
                                                const float* __restrict__ s2){
    int idx = blockIdx.x*256 + threadIdx.x;
    if (idx >= MROWS * (HID/8)) return;
    int r = idx / (HID/8), c8 = idx % (HID/8);
    int b = r / 196;
    int c = c8*8;
    uint4 u = ((uint4*)X)[idx];
    float f[8]; unpack8(u, f);
    const float* sp = s2 + b*HID + c;
    #pragma unroll
    for (int e = 0; e < 8; ++e)
        f[e] = hswish(f[e]*ss[c+e] + ss[HID+c+e]) * sp[e];
    ((uint4*)X)[idx] = pack8(f);
}

// ---------- final ----------
__global__ __launch_bounds__(256) void final_k(const float4* __restrict__ xin,
                                               const float4* __restrict__ f,
                                               const float4* __restrict__ h4,
                                               const float* __restrict__ ss,
                                               float4* __restrict__ outp){
    int idx = blockIdx.x*256 + threadIdx.x;
    if (idx >= 32*197*192) return;
    int b = idx / (197*192);
    int rem = idx % (197*192);
    int n = rem / 192, c4 = rem % 192;
    if (n == 0){ outp[idx] = xin[idx]; return; }
    size_t off = ((size_t)b*196 + n - 1)*192 + c4;
    float4 hv = h4[off];
    float4 fv = f[off];
    float4 o;
    int c = c4*4;
    o.x = fv.x + hv.x*ss[c+0] + ss[CDIM + c+0];
    o.y = fv.y + hv.y*ss[c+1] + ss[CDIM + c+1];
    o.z = fv.z + hv.z*ss[c+2] + ss[CDIM + c+2];
    o.w = fv.w + hv.w*ss[c+3] + ss[CDIM + c+3];
    outp[idx] = o;
}

extern "C" void kernel_launch(void* const* d_in, const int* in_sizes, int n_in,
                              void* d_out, int out_size, void* d_ws, size_t ws_size,
                              hipStream_t stream){
    const float* x      = (const float*)d_in[0];
    const float* w_qkv  = (const float*)d_in[1];
    const float* w_proj = (const float*)d_in[2];
    const float* b_proj = (const float*)d_in[3];
    const float* rpb    = (const float*)d_in[4];
    const float* pw1_w  = (const float*)d_in[5];
    const float* bn1_g  = (const float*)d_in[6];
    const float* bn1_b  = (const float*)d_in[7];
    const float* dw_w   = (const float*)d_in[8];
    const float* bn2_g  = (const float*)d_in[9];
    const float* bn2_b  = (const float*)d_in[10];
    const float* se_w1  = (const float*)d_in[11];
    const float* se_b1  = (const float*)d_in[12];
    const float* se_w2  = (const float*)d_in[13];
    const float* se_b2  = (const float*)d_in[14];
    const float* pw2_w  = (const float*)d_in[15];
    const float* bn3_g  = (const float*)d_in[16];
    const float* bn3_b  = (const float*)d_in[17];

    char* ws = (char*)d_ws;
    ushort_t* win    = (ushort_t*)(ws + 0);
    ushort_t* qkv    = (ushort_t*)(ws + 9633792);
    ushort_t* fbf    = (ushort_t*)(ws + 0);
    ushort_t* pw1b   = (ushort_t*)(ws + 9633792);
    ushort_t* hb     = (ushort_t*)(ws + 0);
    ushort_t* wqkvb  = (ushort_t*)(ws + 38535168);
    ushort_t* attnb  = (ushort_t*)(ws + 38535168);
    ushort_t* wprojb = (ushort_t*)(ws + 48168960);
    ushort_t* ha     = (ushort_t*)(ws + 38535168);
    float*    h4     = (float*)(ws + 38535168);
    ushort_t* pw2b   = (ushort_t*)(ws + 57802752);
    float*    f      = (float*)(ws + 77070336);
    float*    stats  = (float*)(ws + 96337920);
    float*    s      = (float*)(ws + 96362496);
    float*    s1     = (float*)(ws + 96755712);
    float*    s2     = (float*)(ws + 96854016);
    float*    dwwT   = (float*)(ws + 96854016);   // alias s2: dead before se_fc writes s2

    const int vec_rows = (MROWS*192 + 255)/256;
    const int vec_hid8 = (MROWS*(HID/8) + 255)/256;
    const int GY = 56;   // 49 row-blocks padded to multiple of 8 for XCD swizzle

    // early weight prep (regions free at this point)
    dw_transpose<<<(HID*9 + 255)/256, 256, 0, stream>>>(dw_w, dwwT);
    cvt_f2b<<<(QKV3*CDIM/4 + 255)/256, 256, 0, stream>>>((const float4*)w_qkv, (ushort4*)wqkvb, QKV3*CDIM/4);
    cvt_f2b<<<(CDIM*CDIM/4 + 255)/256, 256, 0, stream>>>((const float4*)w_proj, (ushort4*)wprojb, CDIM*CDIM/4);

    // attention half
    gather_win<<<vec_rows, 256, 0, stream>>>((const float4*)x, (ushort4*)win);
    gemm_bt<<<dim3(QKV3/128, GY), 256, 0, stream>>>(win, wqkvb, qkv, nullptr, MROWS, QKV3, CDIM, nullptr, nullptr, 0);
    attn_kernel<<<dim3(12, 128), 256, 0, stream>>>(qkv, attnb, rpb);
    cvt_f2b<<<(HID*CDIM/4 + 255)/256, 256, 0, stream>>>((const float4*)pw1_w, (ushort4*)pw1b, HID*CDIM/4);  // qkv dead
    zero_f32<<<24, 256, 0, stream>>>(stats, 2*HID);   // for fused bn1 stats
    gemm_bt64<<<dim3(CDIM/64, GY), 256, 0, stream>>>(attnb, wprojb, fbf, f, MROWS, CDIM, CDIM, b_proj, nullptr, 1);

    // ConvFFN half
    gemm_bt<<<dim3(HID/128, GY), 256, 0, stream>>>(fbf, pw1b, ha, nullptr, MROWS, HID, CDIM, nullptr, stats, 0);
    bn_finalize<<<HID/256, 256, 0, stream>>>(stats, bn1_g, bn1_b, HID);

    dwconv_v<<<(MROWS*384 + 255)/256, 256, 0, stream>>>(ha, dwwT, stats, hb);   // bn1+hswish fused
    cvt_f2b<<<(CDIM*HID/4 + 255)/256, 256, 0, stream>>>((const float4*)pw2_w, (ushort4*)pw2b, CDIM*HID/4);  // ha dead
    zero_f32<<<24, 256, 0, stream>>>(stats, 2*HID);
    bn_stats<<<dim3(HID/256, 8), 256, 0, stream>>>(hb, stats, HID);
    bn_finalize<<<HID/256, 256, 0, stream>>>(stats, bn2_g, bn2_b, HID);

    se_mean<<<dim3(32, HID/256), 256, 0, stream>>>(hb, stats, s);               // bn2+hswish fused
    se_fc<<<dim3((CDIM*64)/256), 256, 0, stream>>>(s, se_w1, se_b1, s1, HID, CDIM, 0);
    se_fc<<<dim3((HID*64)/256), 256, 0, stream>>>(s1, se_w2, se_b2, s2, CDIM, HID, 1);
    se_scale<<<vec_hid8, 256, 0, stream>>>(hb, stats, s2);                      // bn2+hswish+SE in one pass

    zero_f32<<<6, 256, 0, stream>>>(stats, 2*CDIM);   // for fused bn3 stats
    gemm_bt64<<<dim3(CDIM/64, GY), 256, 0, stream>>>(hb, pw2b, nullptr, h4, MROWS, CDIM, HID, nullptr, stats, 0);
    bn_finalize<<<CDIM/256, 256, 0, stream>>>(stats, bn3_g, bn3_b, CDIM);
    final_k<<<(32*197*192 + 255)/256, 256, 0, stream>>>((const float4*)x, (const float4*)f, (const float4*)h4, stats, (float4*)d_out);
}

// Round 8
// 620.425 us; speedup vs baseline: 2.0974x; 1.0826x over previous
//
#include <hip/hip_runtime.h>
#include <hip/hip_bf16.h>

typedef unsigned short ushort_t;
typedef unsigned int uint_t;
typedef short short8 __attribute__((ext_vector_type(8)));
typedef float floatx4 __attribute__((ext_vector_type(4)));

// ---------- bf16 helpers (raw ushort storage) ----------
__device__ inline float b2f(ushort_t u){
    uint_t v = ((uint_t)u) << 16;
    return __uint_as_float(v);
}
__device__ inline ushort_t f2b(float f){
    uint_t v = __float_as_uint(f);
    uint_t r = (v + 0x7FFFu + ((v >> 16) & 1u)) >> 16;  // RNE
    return (ushort_t)r;
}
__device__ inline void unpack8(uint4 u, float* f){
    uint_t w[4] = {u.x, u.y, u.z, u.w};
    #pragma unroll
    for (int i = 0; i < 4; ++i){
        f[2*i]   = __uint_as_float(w[i] << 16);
        f[2*i+1] = __uint_as_float(w[i] & 0xFFFF0000u);
    }
}
__device__ inline uint4 pack8(const float* f){
    uint4 o;
    uint_t w[4];
    #pragma unroll
    for (int i = 0; i < 4; ++i)
        w[i] = (uint_t)f2b(f[2*i]) | ((uint_t)f2b(f[2*i+1]) << 16);
    o.x = w[0]; o.y = w[1]; o.z = w[2]; o.w = w[3];
    return o;
}
__device__ inline ushort4 cvt4(float4 v){
    ushort4 o;
    o.x = f2b(v.x); o.y = f2b(v.y); o.z = f2b(v.z); o.w = f2b(v.w);
    return o;
}
__device__ inline float hswish(float y){
    return y * fminf(fmaxf(y + 3.f, 0.f), 6.f) * (1.f/6.f);
}

// ---------- constants ----------
#define MROWS 6272
#define CDIM  768
#define HID   3072
#define QKV3  2304

// swin window->spatial row map (with +3 roll): ri (window layout) -> dest row (b*196+p)
__device__ inline int scatter_row(int ri){
    int w  = ri / 49, t = ri % 49;
    int b  = w >> 2,  wi = w & 3;
    int wy = wi >> 1, wx = wi & 1;
    int ty = t / 7,   tx = t % 7;
    int yd = (wy*7 + ty + 3) % 14;
    int xd = (wx*7 + tx + 3) % 14;
    return b*196 + yd*14 + xd;
}

// ---------- fp32 -> bf16 cast (weights) ----------
__global__ __launch_bounds__(256) void cvt_f2b(const float4* __restrict__ in,
                                               ushort4* __restrict__ out, int n4){
    int i = blockIdx.x * 256 + threadIdx.x;
    if (i < n4) out[i] = cvt4(in[i]);
}

// ---------- dw weight transpose: [3072][9] -> [9][3072] ----------
__global__ __launch_bounds__(256) void dw_transpose(const float* __restrict__ w,
                                                    float* __restrict__ wT){
    int i = blockIdx.x*256 + threadIdx.x;
    if (i < HID*9){ int c = i/9, k = i%9; wT[k*HID + c] = w[i]; }
}

// ---------- window gather: x fp32 (B,197,C) -> win bf16 (128*49, C), shifted ----------
__global__ __launch_bounds__(256) void gather_win(const float4* __restrict__ x,
                                                  ushort4* __restrict__ win){
    int idx = blockIdx.x * 256 + threadIdx.x;
    if (idx >= MROWS * 192) return;
    int r  = idx / 192, c4 = idx % 192;
    int w  = r / 49,  t  = r % 49;
    int b  = w >> 2,  wi = w & 3;
    int wy = wi >> 1, wx = wi & 1;
    int ty = t / 7,   tx = t % 7;
    int ys = (wy*7 + ty + 3) % 14;                       // roll(-3)
    int xs = (wx*7 + tx + 3) % 14;
    win[idx] = cvt4(x[(size_t)b*197*192 + (size_t)(1 + ys*14 + xs)*192 + c4]);
}

// ---------- MFMA GEMM 128x128 tile (qkv / pw1) ----------
__global__ __launch_bounds__(256) void gemm_bt(const ushort_t* __restrict__ A,
                                               const ushort_t* __restrict__ B,
                                               ushort_t* __restrict__ Cb,
                                               float* __restrict__ Cf,
                                               int M, int N, int K,
                                               const float* __restrict__ bias,
                                               float* __restrict__ stats,
                                               int scat){
    const int nx   = gridDim.x;
    int flat = blockIdx.y * nx + blockIdx.x;
    int xcd  = flat & 7;
    int k    = flat >> 3;
    int by   = xcd + 8 * (k / nx);
    int bx   = k % nx;
    if (by * 128 >= M) return;

    __shared__ __align__(16) ushort_t As[128*32];
    __shared__ __align__(16) ushort_t Bs[128*32];
    const int tid  = threadIdx.x;
    const int lane = tid & 63;
    const int wid  = tid >> 6;
    const int m0 = by * 128;
    const int n0 = bx * 128;
    const int wm = (wid >> 1) * 64;
    const int wn = (wid & 1) * 64;

    floatx4 acc[4][4] = {};

    for (int k0 = 0; k0 < K; k0 += 32){
        __syncthreads();
        #pragma unroll
        for (int j = 0; j < 2; ++j){
            int ch  = wid*2 + j;
            int row = ch*16 + (lane >> 2);
            int col = (lane & 3) * 8;
            const ushort_t* gA = A + (size_t)(m0 + row)*K + k0 + col;
            const ushort_t* gB = B + (size_t)(n0 + row)*K + k0 + col;
            __builtin_amdgcn_global_load_lds(
                (const __attribute__((address_space(1))) void*)gA,
                (__attribute__((address_space(3))) void*)(As + ch*512 + lane*8), 16, 0, 0);
            __builtin_amdgcn_global_load_lds(
                (const __attribute__((address_space(1))) void*)gB,
                (__attribute__((address_space(3))) void*)(Bs + ch*512 + lane*8), 16, 0, 0);
        }
        __syncthreads();

        short8 af[4], bfr[4];
        const int fr = lane & 15;
        const int co = (lane >> 4) * 8;
        #pragma unroll
        for (int i = 0; i < 4; ++i){
            af[i]  = *(const short8*)(As + (wm + i*16 + fr)*32 + co);
            bfr[i] = *(const short8*)(Bs + (wn + i*16 + fr)*32 + co);
        }
        #pragma unroll
        for (int i = 0; i < 4; ++i)
            #pragma unroll
            for (int j = 0; j < 4; ++j)
                acc[i][j] = __builtin_amdgcn_mfma_f32_16x16x32_bf16(af[i], bfr[j], acc[i][j], 0, 0, 0);
    }

    #pragma unroll
    for (int i = 0; i < 4; ++i){
        int grow = m0 + wm + i*16 + (lane >> 4)*4;
        #pragma unroll
        for (int j = 0; j < 4; ++j){
            int gcol = n0 + wn + j*16 + (lane & 15);
            float bv = bias ? bias[gcol] : 0.f;
            if (scat){
                #pragma unroll
                for (int r = 0; r < 4; ++r){
                    float v = acc[i][j][r] + bv;
                    size_t off = (size_t)scatter_row(grow + r)*N + gcol;
                    Cf[off] = v;
                    Cb[off] = f2b(v);
                }
            } else if (Cb){
                #pragma unroll
                for (int r = 0; r < 4; ++r)
                    Cb[(size_t)(grow + r)*N + gcol] = f2b(acc[i][j][r] + bv);
            } else {
                #pragma unroll
                for (int r = 0; r < 4; ++r)
                    Cf[(size_t)(grow + r)*N + gcol] = acc[i][j][r] + bv;
            }
        }
    }

    if (stats){
        #pragma unroll
        for (int j = 0; j < 4; ++j){
            int gcol = n0 + wn + j*16 + (lane & 15);
            float bv = bias ? bias[gcol] : 0.f;
            float sv = 0.f, sq = 0.f;
            #pragma unroll
            for (int i = 0; i < 4; ++i)
                #pragma unroll
                for (int r = 0; r < 4; ++r){
                    float v = acc[i][j][r] + bv;
                    sv += v; sq += v*v;
                }
            sv += __shfl_xor(sv, 16, 64);  sq += __shfl_xor(sq, 16, 64);
            sv += __shfl_xor(sv, 32, 64);  sq += __shfl_xor(sq, 32, 64);
            if (lane < 16){
                atomicAdd(&stats[gcol], sv);
                atomicAdd(&stats[N + gcol], sq);
            }
        }
    }
}

// ---------- MFMA GEMM 128x64 tile (proj / pw2) ----------
__global__ __launch_bounds__(256) void gemm_bt64(const ushort_t* __restrict__ A,
                                                 const ushort_t* __restrict__ B,
                                                 ushort_t* __restrict__ Cb,
                                                 float* __restrict__ Cf,
                                                 int M, int N, int K,
                                                 const float* __restrict__ bias,
                                                 float* __restrict__ stats,
                                                 int scat){
    const int nx   = gridDim.x;
    int flat = blockIdx.y * nx + blockIdx.x;
    int xcd  = flat & 7;
    int k    = flat >> 3;
    int by   = xcd + 8 * (k / nx);
    int bx   = k % nx;
    if (by * 128 >= M) return;

    __shared__ __align__(16) ushort_t As[128*32];
    __shared__ __align__(16) ushort_t Bs[64*32];
    const int tid  = threadIdx.x;
    const int lane = tid & 63;
    const int wid  = tid >> 6;
    const int m0 = by * 128;
    const int n0 = bx * 64;
    const int wm = (wid >> 1) * 64;
    const int wn = (wid & 1) * 32;

    floatx4 acc[4][2] = {};

    for (int k0 = 0; k0 < K; k0 += 32){
        __syncthreads();
        {
            int row = (lane >> 2);
            int col = (lane & 3) * 8;
            #pragma unroll
            for (int j = 0; j < 2; ++j){
                int ch = wid*2 + j;
                const ushort_t* gA = A + (size_t)(m0 + ch*16 + row)*K + k0 + col;
                __builtin_amdgcn_global_load_lds(
                    (const __attribute__((address_space(1))) void*)gA,
                    (__attribute__((address_space(3))) void*)(As + ch*512 + lane*8), 16, 0, 0);
            }
            const ushort_t* gB = B + (size_t)(n0 + wid*16 + row)*K + k0 + col;
            __builtin_amdgcn_global_load_lds(
                (const __attribute__((address_space(1))) void*)gB,
                (__attribute__((address_space(3))) void*)(Bs + wid*512 + lane*8), 16, 0, 0);
        }
        __syncthreads();

        short8 af[4], bfr[2];
        const int fr = lane & 15;
        const int co = (lane >> 4) * 8;
        #pragma unroll
        for (int i = 0; i < 4; ++i)
            af[i]  = *(const short8*)(As + (wm + i*16 + fr)*32 + co);
        #pragma unroll
        for (int j = 0; j < 2; ++j)
            bfr[j] = *(const short8*)(Bs + (wn + j*16 + fr)*32 + co);
        #pragma unroll
        for (int i = 0; i < 4; ++i)
            #pragma unroll
            for (int j = 0; j < 2; ++j)
                acc[i][j] = __builtin_amdgcn_mfma_f32_16x16x32_bf16(af[i], bfr[j], acc[i][j], 0, 0, 0);
    }

    #pragma unroll
    for (int i = 0; i < 4; ++i){
        int grow = m0 + wm + i*16 + (lane >> 4)*4;
        #pragma unroll
        for (int j = 0; j < 2; ++j){
            int gcol = n0 + wn + j*16 + (lane & 15);
            float bv = bias ? bias[gcol] : 0.f;
            if (scat){
                #pragma unroll
                for (int r = 0; r < 4; ++r){
                    float v = acc[i][j][r] + bv;
                    size_t off = (size_t)scatter_row(grow + r)*N + gcol;
                    Cf[off] = v;
                    Cb[off] = f2b(v);
                }
            } else if (Cb){
                #pragma unroll
                for (int r = 0; r < 4; ++r)
                    Cb[(size_t)(grow + r)*N + gcol] = f2b(acc[i][j][r] + bv);
            } else {
                #pragma unroll
                for (int r = 0; r < 4; ++r)
                    Cf[(size_t)(grow + r)*N + gcol] = acc[i][j][r] + bv;
            }
        }
    }

    if (stats){
        #pragma unroll
        for (int j = 0; j < 2; ++j){
            int gcol = n0 + wn + j*16 + (lane & 15);
            float bv = bias ? bias[gcol] : 0.f;
            float sv = 0.f, sq = 0.f;
            #pragma unroll
            for (int i = 0; i < 4; ++i)
                #pragma unroll
                for (int r = 0; r < 4; ++r){
                    float v = acc[i][j][r] + bv;
                    sv += v; sq += v*v;
                }
            sv += __shfl_xor(sv, 16, 64);  sq += __shfl_xor(sq, 16, 64);
            sv += __shfl_xor(sv, 32, 64);  sq += __shfl_xor(sq, 32, 64);
            if (lane < 16){
                atomicAdd(&stats[gcol], sv);
                atomicAdd(&stats[N + gcol], sq);
            }
        }
    }
}

// ---------- bias+mask table: bm[h][wi][64][64], padded entries = -1e30 ----------
__global__ __launch_bounds__(256) void bm_precompute(const float* __restrict__ rpb,
                                                     float* __restrict__ bm){
    int idx = blockIdx.x*256 + threadIdx.x;      // 12*4*64*64
    if (idx >= 12*4*64*64) return;
    int ki = idx & 63, qi = (idx >> 6) & 63, wi = (idx >> 12) & 3, h = idx >> 14;
    float v = -1e30f;
    if (qi < 49 && ki < 49){
        int qy = qi/7, qx = qi%7, ky = ki/7, kx = ki%7;
        int ridx = (qy - ky + 6)*13 + (qx - kx + 6);
        v = rpb[ridx*12 + h];
        int wy = wi >> 1, wx = wi & 1;
        int gqy = wy*7 + qy, gqx = wx*7 + qx, gky = wy*7 + ky, gkx = wx*7 + kx;
        int cq = ((gqy < 7) ? 0 : (gqy < 11 ? 1 : 2))*3 + ((gqx < 7) ? 0 : (gqx < 11 ? 1 : 2));
        int ck = ((gky < 7) ? 0 : (gky < 11 ? 1 : 2))*3 + ((gkx < 7) ? 0 : (gkx < 11 ? 1 : 2));
        if (cq != ck) v -= 100.f;
    }
    bm[idx] = v;
}

// ---------- MFMA attention: block = (head, window), 4 waves = 4 Q row-tiles ----------
// QK^T/PV fragments per gemm_bt-verified layout: A[m=lane&15][k=quad*8+j],
// B[k=quad*8+j][n=lane&15]; C/D col=lane&15, row=quad*4+r.
__global__ __launch_bounds__(256) void attn_mfma(const ushort_t* __restrict__ qkv,
                                                 ushort_t* __restrict__ outp,
                                                 const float* __restrict__ bm){
    __shared__ __align__(16) ushort_t Ps[64*72];   // P (softmax probs), stride 72 bf16
    __shared__ __align__(16) ushort_t VT[64*72];   // V^T: VT[n][k]
    const int tid = threadIdx.x, lane = tid & 63, wid = tid >> 6;
    const int h = blockIdx.x, w = blockIdx.y, wi = w & 3;
    const int fr = lane & 15, quad = lane >> 4, co = quad*8;

    // stage V^T (zero-fill k>=49)
    for (int idx = tid; idx < 64*64; idx += 256){
        int k = idx >> 6, n = idx & 63;
        ushort_t v = 0;
        if (k < 49) v = qkv[(size_t)(w*49 + k)*QKV3 + 1536 + h*64 + n];
        VT[n*72 + k] = v;
    }
    __syncthreads();

    // QK^T: wave wid owns Q rows [wid*16, wid*16+16)
    floatx4 accs[4] = {};
    const ushort_t* qbase = qkv + (size_t)(w*49 + wid*16 + fr)*QKV3 + h*64;
    #pragma unroll
    for (int k0 = 0; k0 < 64; k0 += 32){
        short8 af = *(const short8*)(qbase + k0 + co);
        #pragma unroll
        for (int j = 0; j < 4; ++j){
            const ushort_t* kbase = qkv + (size_t)(w*49 + j*16 + fr)*QKV3 + 768 + h*64;
            short8 bf = *(const short8*)(kbase + k0 + co);
            accs[j] = __builtin_amdgcn_mfma_f32_16x16x32_bf16(af, bf, accs[j], 0, 0, 0);
        }
    }

    // scale + bias + mask + softmax (per quad-row), write P to LDS as bf16
    const float* bmh = bm + (size_t)((h*4 + wi)*64 + wid*16)*64;
    #pragma unroll
    for (int r = 0; r < 4; ++r){
        int lrow = quad*4 + r;
        float m = -3e38f;
        #pragma unroll
        for (int j = 0; j < 4; ++j){
            float a = accs[j][r]*0.125f + bmh[lrow*64 + j*16 + fr];
            accs[j][r] = a;
            m = fmaxf(m, a);
        }
        #pragma unroll
        for (int off = 1; off < 16; off <<= 1) m = fmaxf(m, __shfl_xor(m, off, 64));
        float s = 0.f;
        #pragma unroll
        for (int j = 0; j < 4; ++j){
            float e = __expf(accs[j][r] - m);
            accs[j][r] = e; s += e;
        }
        #pragma unroll
        for (int off = 1; off < 16; off <<= 1) s += __shfl_xor(s, off, 64);
        float inv = 1.f / s;
        #pragma unroll
        for (int j = 0; j < 4; ++j)
            Ps[(wid*16 + lrow)*72 + j*16 + fr] = f2b(accs[j][r]*inv);
    }
    __syncthreads();

    // PV: O tile 16x64 per wave
    floatx4 acco[4] = {};
    #pragma unroll
    for (int k0 = 0; k0 < 64; k0 += 32){
        short8 af = *(const short8*)(Ps + (wid*16 + fr)*72 + k0 + co);
        #pragma unroll
        for (int j = 0; j < 4; ++j){
            short8 bf = *(const short8*)(VT + (j*16 + fr)*72 + k0 + co);
            acco[j] = __builtin_amdgcn_mfma_f32_16x16x32_bf16(af, bf, acco[j], 0, 0, 0);
        }
    }
    #pragma unroll
    for (int r = 0; r < 4; ++r){
        int qi = wid*16 + quad*4 + r;
        if (qi < 49){
            #pragma unroll
            for (int j = 0; j < 4; ++j)
                outp[(size_t)(w*49 + qi)*CDIM + h*64 + j*16 + fr] = f2b(acco[j][r]);
        }
    }
}

// ---------- BN ----------
__global__ void zero_f32(float* __restrict__ p, int n){
    int i = blockIdx.x*256 + threadIdx.x;
    if (i < n) p[i] = 0.f;
}
__global__ __launch_bounds__(256) void bn_stats(const ushort_t* __restrict__ X,
                                                float* __restrict__ sums, int Cch){
    int c  = blockIdx.x*256 + threadIdx.x;
    int r0 = blockIdx.y * 784;
    float s = 0.f, s2 = 0.f;
    for (int r = r0; r < r0 + 784; ++r){
        float v = b2f(X[(size_t)r*Cch + c]);
        s += v; s2 += v*v;
    }
    atomicAdd(&sums[c], s);
    atomicAdd(&sums[Cch + c], s2);
}
__global__ void bn_finalize(float* __restrict__ sums, const float* __restrict__ g,
                            const float* __restrict__ b, int Cch){
    int c = blockIdx.x*256 + threadIdx.x;
    if (c >= Cch) return;
    float mean = sums[c] * (1.f/6272.f);
    float var  = sums[Cch + c] * (1.f/6272.f) - mean*mean;
    float sc = g[c] * rsqrtf(var + 1e-5f);
    sums[c] = sc;
    sums[Cch + c] = b[c] - mean*sc;
}

// ---------- depthwise 3x3, vectorized, bn1+hswish fused on input ----------
__global__ __launch_bounds__(256) void dwconv_v(const ushort_t* __restrict__ in,
                                                const float* __restrict__ wT,
                                                const float* __restrict__ ss,
                                                ushort_t* __restrict__ out){
    int idx = blockIdx.x*256 + threadIdx.x;      // over MROWS*384
    if (idx >= MROWS*384) return;
    int r  = idx / 384, cg = idx % 384;
    int b  = r / 196,  p  = r % 196;
    int y  = p / 14,   x  = p % 14;
    int c  = cg*8;
    const uint4* inb = (const uint4*)(in + (size_t)b*196*HID);
    float sc[8], sh[8];
    {
        const float4* s0 = (const float4*)(ss + c);
        const float4* s1 = (const float4*)(ss + HID + c);
        float4 a0 = s0[0], a1 = s0[1], b0 = s1[0], b1 = s1[1];
        sc[0]=a0.x; sc[1]=a0.y; sc[2]=a0.z; sc[3]=a0.w;
        sc[4]=a1.x; sc[5]=a1.y; sc[6]=a1.z; sc[7]=a1.w;
        sh[0]=b0.x; sh[1]=b0.y; sh[2]=b0.z; sh[3]=b0.w;
        sh[4]=b1.x; sh[5]=b1.y; sh[6]=b1.z; sh[7]=b1.w;
    }
    float acc[8] = {};
    #pragma unroll
    for (int ky = 0; ky < 3; ++ky){
        int yy = y + ky - 1;
        if ((unsigned)yy >= 14u) continue;
        #pragma unroll
        for (int kx = 0; kx < 3; ++kx){
            int xx = x + kx - 1;
            if ((unsigned)xx >= 14u) continue;
            uint4 u = inb[(yy*14 + xx)*384 + cg];
            float fin[8]; unpack8(u, fin);
            const float4* wp = (const float4*)(wT + (ky*3 + kx)*HID + c);
            float4 w0 = wp[0], w1 = wp[1];
            float wv[8] = {w0.x,w0.y,w0.z,w0.w,w1.x,w1.y,w1.z,w1.w};
            #pragma unroll
            for (int e = 0; e < 8; ++e)
                acc[e] += hswish(fin[e]*sc[e] + sh[e]) * wv[e];
        }
    }
    ((uint4*)out)[idx] = pack8(acc);
}

// ---------- SE (bn2+hswish fused on read) ----------
__global__ __launch_bounds__(256) void se_mean(const ushort_t* __restrict__ X,
                                               const float* __restrict__ ss,
                                               float* __restrict__ s){
    int b = blockIdx.x;
    int c = blockIdx.y*256 + threadIdx.x;
    float sc = ss[c], sh = ss[HID + c];
    float a = 0.f;
    for (int p = 0; p < 196; ++p)
        a += hswish(b2f(X[((size_t)b*196 + p)*HID + c])*sc + sh);
    s[b*HID + c] = a * (1.f/196.f);
}
__global__ __launch_bounds__(256) void se_fc(const float* __restrict__ in,
                                             const float* __restrict__ w,
                                             const float* __restrict__ bias,
                                             float* __restrict__ out,
                                             int IN, int OUT, int mode){
    int wv   = (blockIdx.x*256 + threadIdx.x) >> 6;
    int lane = threadIdx.x & 63;
    if (wv >= OUT) return;
    const float* wr = w + (size_t)wv * IN;
    float acc[32];
    #pragma unroll
    for (int b = 0; b < 32; ++b) acc[b] = 0.f;
    for (int k = lane; k < IN; k += 64){
        float wval = wr[k];
        #pragma unroll
        for (int b = 0; b < 32; ++b)
            acc[b] += in[b*IN + k] * wval;
    }
    #pragma unroll
    for (int b = 0; b < 32; ++b){
        float v = acc[b];
        #pragma unroll
        for (int off = 32; off; off >>= 1) v += __shfl_down(v, off, 64);
        if (lane == 0){
            float a = v + bias[wv];
            if (mode == 0) a = fmaxf(a, 0.f);
            else           a = fminf(fmaxf(a + 3.f, 0.f), 6.f) * (1.f/6.f);
            out[b*OUT + wv] = a;
        }
    }
}
// bn2+hswish+SE-scale in one pass
__global__ __launch_bounds__(256) void se_scale(ushort_t* __restrict__ X,
                                                const float* __restrict__ ss,
                                                const float* __restrict__ s2){
    int idx = blockIdx.x*256 + threadIdx.x;
    if (idx >= MROWS * (HID/8)) return;
    int r = idx / (HID/8), c8 = idx % (HID/8);
    int b = r / 196;
    int c = c8*8;
    uint4 u = ((uint4*)X)[idx];
    float f[8]; unpack8(u, f);
    const float* sp = s2 + b*HID + c;
    #pragma unroll
    for (int e = 0; e < 8; ++e)
        f[e] = hswish(f[e]*ss[c+e] + ss[HID+c+e]) * sp[e];
    ((uint4*)X)[idx] = pack8(f);
}

// ---------- final ----------
__global__ __launch_bounds__(256) void final_k(const float4* __restrict__ xin,
                                               const float4* __restrict__ f,
                                               const float4* __restrict__ h4,
                                               const float* __restrict__ ss,
                                               float4* __restrict__ outp){
    int idx = blockIdx.x*256 + threadIdx.x;
    if (idx >= 32*197*192) return;
    int b = idx / (197*192);
    int rem = idx % (197*192);
    int n = rem / 192, c4 = rem % 192;
    if (n == 0){ outp[idx] = xin[idx]; return; }
    size_t off = ((size_t)b*196 + n - 1)*192 + c4;
    float4 hv = h4[off];
    float4 fv = f[off];
    float4 o;
    int c = c4*4;
    o.x = fv.x + hv.x*ss[c+0] + ss[CDIM + c+0];
    o.y = fv.y + hv.y*ss[c+1] + ss[CDIM + c+1];
    o.z = fv.z + hv.z*ss[c+2] + ss[CDIM + c+2];
    o.w = fv.w + hv.w*ss[c+3] + ss[CDIM + c+3];
    outp[idx] = o;
}

extern "C" void kernel_launch(void* const* d_in, const int* in_sizes, int n_in,
                              void* d_out, int out_size, void* d_ws, size_t ws_size,
                              hipStream_t stream){
    const float* x      = (const float*)d_in[0];
    const float* w_qkv  = (const float*)d_in[1];
    const float* w_proj = (const float*)d_in[2];
    const float* b_proj = (const float*)d_in[3];
    const float* rpb    = (const float*)d_in[4];
    const float* pw1_w  = (const float*)d_in[5];
    const float* bn1_g  = (const float*)d_in[6];
    const float* bn1_b  = (const float*)d_in[7];
    const float* dw_w   = (const float*)d_in[8];
    const float* bn2_g  = (const float*)d_in[9];
    const float* bn2_b  = (const float*)d_in[10];
    const float* se_w1  = (const float*)d_in[11];
    const float* se_b1  = (const float*)d_in[12];
    const float* se_w2  = (const float*)d_in[13];
    const float* se_b2  = (const float*)d_in[14];
    const float* pw2_w  = (const float*)d_in[15];
    const float* bn3_g  = (const float*)d_in[16];
    const float* bn3_b  = (const float*)d_in[17];

    char* ws = (char*)d_ws;
    ushort_t* win    = (ushort_t*)(ws + 0);
    float*    bm     = (float*)(ws + 0);          // alias win: dead after qkv gemm, before proj gemm
    ushort_t* qkv    = (ushort_t*)(ws + 9633792);
    ushort_t* fbf    = (ushort_t*)(ws + 0);
    ushort_t* pw1b   = (ushort_t*)(ws + 9633792);
    ushort_t* hb     = (ushort_t*)(ws + 0);
    ushort_t* wqkvb  = (ushort_t*)(ws + 38535168);
    ushort_t* attnb  = (ushort_t*)(ws + 38535168);
    ushort_t* wprojb = (ushort_t*)(ws + 48168960);
    ushort_t* ha     = (ushort_t*)(ws + 38535168);
    float*    h4     = (float*)(ws + 38535168);
    ushort_t* pw2b   = (ushort_t*)(ws + 57802752);
    float*    f      = (float*)(ws + 77070336);
    float*    stats  = (float*)(ws + 96337920);
    float*    s      = (float*)(ws + 96362496);
    float*    s1     = (float*)(ws + 96755712);
    float*    s2     = (float*)(ws + 96854016);
    float*    dwwT   = (float*)(ws + 96854016);   // alias s2: dead before se_fc writes s2

    const int vec_rows = (MROWS*192 + 255)/256;
    const int vec_hid8 = (MROWS*(HID/8) + 255)/256;
    const int GY = 56;   // 49 row-blocks padded to multiple of 8 for XCD swizzle

    // early weight prep
    dw_transpose<<<(HID*9 + 255)/256, 256, 0, stream>>>(dw_w, dwwT);
    cvt_f2b<<<(QKV3*CDIM/4 + 255)/256, 256, 0, stream>>>((const float4*)w_qkv, (ushort4*)wqkvb, QKV3*CDIM/4);
    cvt_f2b<<<(CDIM*CDIM/4 + 255)/256, 256, 0, stream>>>((const float4*)w_proj, (ushort4*)wprojb, CDIM*CDIM/4);

    // attention half
    gather_win<<<vec_rows, 256, 0, stream>>>((const float4*)x, (ushort4*)win);
    gemm_bt<<<dim3(QKV3/128, GY), 256, 0, stream>>>(win, wqkvb, qkv, nullptr, MROWS, QKV3, CDIM, nullptr, nullptr, 0);
    bm_precompute<<<(12*4*64*64)/256, 256, 0, stream>>>(rpb, bm);   // win dead now
    attn_mfma<<<dim3(12, 128), 256, 0, stream>>>(qkv, attnb, bm);
    cvt_f2b<<<(HID*CDIM/4 + 255)/256, 256, 0, stream>>>((const float4*)pw1_w, (ushort4*)pw1b, HID*CDIM/4);  // qkv dead
    zero_f32<<<24, 256, 0, stream>>>(stats, 2*HID);   // for fused bn1 stats
    gemm_bt64<<<dim3(CDIM/64, GY), 256, 0, stream>>>(attnb, wprojb, fbf, f, MROWS, CDIM, CDIM, b_proj, nullptr, 1);

    // ConvFFN half
    gemm_bt<<<dim3(HID/128, GY), 256, 0, stream>>>(fbf, pw1b, ha, nullptr, MROWS, HID, CDIM, nullptr, stats, 0);
    bn_finalize<<<HID/256, 256, 0, stream>>>(stats, bn1_g, bn1_b, HID);

    dwconv_v<<<(MROWS*384 + 255)/256, 256, 0, stream>>>(ha, dwwT, stats, hb);   // bn1+hswish fused
    cvt_f2b<<<(CDIM*HID/4 + 255)/256, 256, 0, stream>>>((const float4*)pw2_w, (ushort4*)pw2b, CDIM*HID/4);  // ha dead
    zero_f32<<<24, 256, 0, stream>>>(stats, 2*HID);
    bn_stats<<<dim3(HID/256, 8), 256, 0, stream>>>(hb, stats, HID);
    bn_finalize<<<HID/256, 256, 0, stream>>>(stats, bn2_g, bn2_b, HID);

    se_mean<<<dim3(32, HID/256), 256, 0, stream>>>(hb, stats, s);               // bn2+hswish fused
    se_fc<<<dim3((CDIM*64)/256), 256, 0, stream>>>(s, se_w1, se_b1, s1, HID, CDIM, 0);
    se_fc<<<dim3((HID*64)/256), 256, 0, stream>>>(s1, se_w2, se_b2, s2, CDIM, HID, 1);
    se_scale<<<vec_hid8, 256, 0, stream>>>(hb, stats, s2);                      // bn2+hswish+SE in one pass

    zero_f32<<<6, 256, 0, stream>>>(stats, 2*CDIM);   // for fused bn3 stats
    gemm_bt64<<<dim3(CDIM/64, GY), 256, 0, stream>>>(hb, pw2b, nullptr, h4, MROWS, CDIM, HID, nullptr, stats, 0);
    bn_finalize<<<CDIM/256, 256, 0, stream>>>(stats, bn3_g, bn3_b, CDIM);
    final_k<<<(32*197*192 + 255)/256, 256, 0, stream>>>((const float4*)x, (const float4*)f, (const float4*)h4, stats, (float4*)d_out);
}